// Round 1
// baseline (620.203 us; speedup 1.0000x reference)
//
#include <hip/hip_runtime.h>
#include <math.h>

constexpr int N = 50000;   // nodes
constexpr int E = 800000;  // edges (without self-loops)
constexpr int F = 128;     // features / hidden
constexpr int G = 256;     // graphs
constexpr int T = 4;       // tasks

// ---------------- degree histogram ----------------
__global__ void k_deg(const int* __restrict__ dst, int* __restrict__ deg) {
    int e = blockIdx.x * blockDim.x + threadIdx.x;
    if (e < E) atomicAdd(&deg[dst[e]], 1);
}

// ---------------- exclusive scan (single block) + dinv ----------------
__global__ __launch_bounds__(1024) void k_scan(const int* __restrict__ deg,
                                               int* __restrict__ rowstart,
                                               int* __restrict__ fillpos,
                                               float* __restrict__ dinv) {
    __shared__ int part[1024];
    int t = threadIdx.x;
    constexpr int CH = (N + 1023) / 1024;  // 49
    int beg = t * CH;
    int end = (beg + CH < N) ? beg + CH : N;
    int s = 0;
    for (int i = beg; i < end; ++i) s += deg[i];
    part[t] = s;
    __syncthreads();
    // Hillis-Steele inclusive scan
    for (int off = 1; off < 1024; off <<= 1) {
        int v = (t >= off) ? part[t - off] : 0;
        __syncthreads();
        part[t] += v;
        __syncthreads();
    }
    int run = (t == 0) ? 0 : part[t - 1];
    for (int i = beg; i < end; ++i) {
        rowstart[i] = run;
        fillpos[i] = run;
        run += deg[i];
        dinv[i] = rsqrtf((float)(deg[i] + 1));  // +1 self-loop
    }
    if (t == 1023) rowstart[N] = part[1023];
}

// ---------------- CSR fill + per-edge coefficient ----------------
__global__ void k_fill(const int* __restrict__ src, const int* __restrict__ dst,
                       int* __restrict__ fillpos, const float* __restrict__ dinv,
                       int* __restrict__ csr_src, float* __restrict__ csr_coef) {
    int e = blockIdx.x * blockDim.x + threadIdx.x;
    if (e >= E) return;
    int d = dst[e], s = src[e];
    int pos = atomicAdd(&fillpos[d], 1);
    csr_src[pos] = s;
    csr_coef[pos] = dinv[s] * dinv[d];
}

// ---------------- C[N,128] = A[N,128] @ W[128,128]  (fp32, tiled) ----------------
__global__ __launch_bounds__(256) void k_gemm(const float* __restrict__ A,
                                              const float* __restrict__ W,
                                              float* __restrict__ C) {
    // A^T tile in LDS: [k][row], leading dim 68 (pad 4 keeps 16B align, breaks bank stride)
    __shared__ __align__(16) float Alds[128 * 68];
    int tid = threadIdx.x;
    int row0 = blockIdx.x * 64;

    for (int f = tid; f < 64 * 32; f += 256) {   // 2048 float4 elements
        int r = f >> 5;        // row within tile 0..63
        int kq = f & 31;       // float4 index along K
        int row = row0 + r;
        float4 v = make_float4(0.f, 0.f, 0.f, 0.f);
        if (row < N) v = ((const float4*)A)[row * 32 + kq];
        Alds[(4 * kq + 0) * 68 + r] = v.x;
        Alds[(4 * kq + 1) * 68 + r] = v.y;
        Alds[(4 * kq + 2) * 68 + r] = v.z;
        Alds[(4 * kq + 3) * 68 + r] = v.w;
    }
    __syncthreads();

    int tx = tid & 31;   // col group: cols 4*tx..4*tx+3
    int ty = tid >> 5;   // row group: rows 8*ty..8*ty+7
    float acc[8][4];
#pragma unroll
    for (int r = 0; r < 8; ++r)
#pragma unroll
        for (int c = 0; c < 4; ++c) acc[r][c] = 0.f;

    const float4* W4 = (const float4*)W;
#pragma unroll 4
    for (int k = 0; k < 128; ++k) {
        float4 w = W4[k * 32 + tx];
        const float4* ap = (const float4*)&Alds[k * 68 + 8 * ty];
        float4 a0 = ap[0], a1 = ap[1];
        float a[8] = {a0.x, a0.y, a0.z, a0.w, a1.x, a1.y, a1.z, a1.w};
#pragma unroll
        for (int r = 0; r < 8; ++r) {
            acc[r][0] = fmaf(a[r], w.x, acc[r][0]);
            acc[r][1] = fmaf(a[r], w.y, acc[r][1]);
            acc[r][2] = fmaf(a[r], w.z, acc[r][2]);
            acc[r][3] = fmaf(a[r], w.w, acc[r][3]);
        }
    }
#pragma unroll
    for (int r = 0; r < 8; ++r) {
        int row = row0 + 8 * ty + r;
        if (row < N) {
            float4 o = make_float4(acc[r][0], acc[r][1], acc[r][2], acc[r][3]);
            ((float4*)C)[row * 32 + tx] = o;
        }
    }
}

// ---------------- gather aggregation + bias + relu ----------------
__global__ __launch_bounds__(256) void k_agg(const float* __restrict__ tmp,
                                             const int* __restrict__ csr_src,
                                             const float* __restrict__ csr_coef,
                                             const int* __restrict__ rowstart,
                                             const float* __restrict__ dinv,
                                             const float* __restrict__ bias,
                                             float* __restrict__ out) {
    int node = (blockIdx.x * blockDim.x + threadIdx.x) >> 5;
    int lane = threadIdx.x & 31;
    if (node >= N) return;
    const float4* t4 = (const float4*)tmp;
    float di = dinv[node];
    float c0 = di * di;                       // self-loop coefficient
    float4 v = t4[node * 32 + lane];
    float4 acc = make_float4(v.x * c0, v.y * c0, v.z * c0, v.w * c0);
    int jb = rowstart[node], je = rowstart[node + 1];
    for (int j = jb; j < je; ++j) {
        int s = csr_src[j];
        float c = csr_coef[j];
        float4 u = t4[s * 32 + lane];
        acc.x = fmaf(u.x, c, acc.x);
        acc.y = fmaf(u.y, c, acc.y);
        acc.z = fmaf(u.z, c, acc.z);
        acc.w = fmaf(u.w, c, acc.w);
    }
    float4 b = ((const float4*)bias)[lane];
    float4 o;
    o.x = fmaxf(acc.x + b.x, 0.f);
    o.y = fmaxf(acc.y + b.y, 0.f);
    o.z = fmaxf(acc.z + b.z, 0.f);
    o.w = fmaxf(acc.w + b.w, 0.f);
    ((float4*)out)[node * 32 + lane] = o;
}

// ---------------- mean-pool accumulate (batch is sorted) ----------------
__global__ void k_pool(const float* __restrict__ h, const int* __restrict__ batch,
                       float* __restrict__ sums) {
    int grp = (blockIdx.x * blockDim.x + threadIdx.x) >> 5;
    int lane = threadIdx.x & 31;
    int base = grp * 64;
    if (base >= N) return;
    int end = (base + 64 < N) ? base + 64 : N;
    float4 acc = make_float4(0.f, 0.f, 0.f, 0.f);
    const float4* h4 = (const float4*)h;
    int curb = batch[base];
    for (int i = base; i < end; ++i) {
        int b = batch[i];
        if (b != curb) {
            float* sp = &sums[curb * F + lane * 4];
            atomicAdd(sp + 0, acc.x); atomicAdd(sp + 1, acc.y);
            atomicAdd(sp + 2, acc.z); atomicAdd(sp + 3, acc.w);
            acc = make_float4(0.f, 0.f, 0.f, 0.f);
            curb = b;
        }
        float4 v = h4[i * 32 + lane];
        acc.x += v.x; acc.y += v.y; acc.z += v.z; acc.w += v.w;
    }
    float* sp = &sums[curb * F + lane * 4];
    atomicAdd(sp + 0, acc.x); atomicAdd(sp + 1, acc.y);
    atomicAdd(sp + 2, acc.z); atomicAdd(sp + 3, acc.w);
}

__global__ void k_cnt(const int* __restrict__ batch, float* __restrict__ cnt) {
    int i = blockIdx.x * blockDim.x + threadIdx.x;
    if (i < N) atomicAdd(&cnt[batch[i]], 1.0f);
}

// ---------------- z = relu(pooled @ Wfc + bfc) ----------------
__global__ __launch_bounds__(128) void k_fc(const float* __restrict__ sums,
                                            const float* __restrict__ cnt,
                                            const float* __restrict__ Wfc,
                                            const float* __restrict__ bfc,
                                            float* __restrict__ z) {
    __shared__ float p[128];
    int g = blockIdx.x, t = threadIdx.x;
    float inv = 1.0f / fmaxf(cnt[g], 1.0f);
    p[t] = sums[g * F + t] * inv;
    __syncthreads();
    float acc = bfc[t];
    for (int k = 0; k < F; ++k) acc = fmaf(p[k], Wfc[k * F + t], acc);
    z[g * F + t] = fmaxf(acc, 0.f);
}

// ---------------- out[t,g,c] = z[g,:] . Wh[t,:,c] + bh[t,c] ----------------
__global__ void k_head(const float* __restrict__ z, const float* __restrict__ Wh,
                       const float* __restrict__ bh, float* __restrict__ out) {
    int o = blockIdx.x * blockDim.x + threadIdx.x;
    if (o >= T * G * 2) return;
    int tt = o >> 9;        // / (G*2)
    int rem = o & 511;
    int g = rem >> 1;
    int c = rem & 1;
    float acc = bh[tt * 2 + c];
    const float* zr = &z[g * F];
    const float* wr = &Wh[tt * F * 2 + c];
    for (int h = 0; h < F; ++h) acc = fmaf(zr[h], wr[h * 2], acc);
    out[o] = acc;
}

extern "C" void kernel_launch(void* const* d_in, const int* in_sizes, int n_in,
                              void* d_out, int out_size, void* d_ws, size_t ws_size,
                              hipStream_t stream) {
    const float* x    = (const float*)d_in[0];
    const int*   ei   = (const int*)d_in[1];      // [2,E]: row0=src, row1=dst
    const int*   batch= (const int*)d_in[2];
    const float* W1   = (const float*)d_in[3];
    const float* b1   = (const float*)d_in[4];
    const float* W2   = (const float*)d_in[5];
    const float* b2   = (const float*)d_in[6];
    const float* Wfc  = (const float*)d_in[7];
    const float* bfc  = (const float*)d_in[8];
    const float* Wh   = (const float*)d_in[9];
    const float* bh   = (const float*)d_in[10];
    float* out = (float*)d_out;

    const int* srcp = ei;
    const int* dstp = ei + E;

    char* w = (char*)d_ws;
    auto alloc = [&](size_t bytes) {
        char* p = w;
        w += (bytes + 255) & ~(size_t)255;
        return p;
    };
    float* tmp      = (float*)alloc((size_t)N * F * 4);
    float* hbuf     = (float*)alloc((size_t)N * F * 4);
    int*   csr_src  = (int*)  alloc((size_t)E * 4);
    float* csr_coef = (float*)alloc((size_t)E * 4);
    int*   rowstart = (int*)  alloc((size_t)(N + 1) * 4);
    int*   fillpos  = (int*)  alloc((size_t)N * 4);
    int*   deg      = (int*)  alloc((size_t)N * 4);
    float* dinv     = (float*)alloc((size_t)N * 4);
    float* sums     = (float*)alloc((size_t)G * F * 4);
    float* cnt      = (float*)alloc((size_t)G * 4);
    float* z        = (float*)alloc((size_t)G * F * 4);

    hipMemsetAsync(deg, 0, (size_t)N * 4, stream);
    hipMemsetAsync(sums, 0, (size_t)G * F * 4, stream);
    hipMemsetAsync(cnt, 0, (size_t)G * 4, stream);

    // CSR build
    k_deg<<<(E + 255) / 256, 256, 0, stream>>>(dstp, deg);
    k_scan<<<1, 1024, 0, stream>>>(deg, rowstart, fillpos, dinv);
    k_fill<<<(E + 255) / 256, 256, 0, stream>>>(srcp, dstp, fillpos, dinv, csr_src, csr_coef);

    // layer 1
    k_gemm<<<(N + 63) / 64, 256, 0, stream>>>(x, W1, tmp);
    k_agg<<<(N * 32 + 255) / 256, 256, 0, stream>>>(tmp, csr_src, csr_coef, rowstart, dinv, b1, hbuf);
    // layer 2
    k_gemm<<<(N + 63) / 64, 256, 0, stream>>>(hbuf, W2, tmp);
    k_agg<<<(N * 32 + 255) / 256, 256, 0, stream>>>(tmp, csr_src, csr_coef, rowstart, dinv, b2, hbuf);

    // pooling
    int ngrp = (N + 63) / 64;
    k_pool<<<(ngrp * 32 + 255) / 256, 256, 0, stream>>>(hbuf, batch, sums);
    k_cnt<<<(N + 255) / 256, 256, 0, stream>>>(batch, cnt);

    // fc + heads
    k_fc<<<G, 128, 0, stream>>>(sums, cnt, Wfc, bfc, z);
    k_head<<<(T * G * 2 + 255) / 256, 256, 0, stream>>>(z, Wh, bh, out);
}

// Round 2
// 496.267 us; speedup vs baseline: 1.2497x; 1.2497x over previous
//
#include <hip/hip_runtime.h>
#include <math.h>

constexpr int N = 50000;   // nodes
constexpr int E = 800000;  // edges (without self-loops)
constexpr int F = 128;     // features / hidden
constexpr int G = 256;     // graphs
constexpr int T = 4;       // tasks

constexpr int SCAN_B = 256;
constexpr int NBLK = (N + SCAN_B - 1) / SCAN_B;  // 196

// ---------------- degree histogram ----------------
__global__ void k_deg(const int* __restrict__ dst, int* __restrict__ deg) {
    int e = blockIdx.x * blockDim.x + threadIdx.x;
    if (e < E) atomicAdd(&deg[dst[e]], 1);
}

// ---------------- two-level scan: block partials + dinv ----------------
__global__ __launch_bounds__(SCAN_B) void k_part(const int* __restrict__ deg,
                                                 int* __restrict__ part,
                                                 float* __restrict__ dinv) {
    __shared__ int s[SCAN_B];
    int t = threadIdx.x;
    int i = blockIdx.x * SCAN_B + t;
    int v = (i < N) ? deg[i] : 0;
    if (i < N) dinv[i] = rsqrtf((float)(v + 1));  // +1 self-loop
    s[t] = v;
    __syncthreads();
#pragma unroll
    for (int off = SCAN_B / 2; off > 0; off >>= 1) {
        if (t < off) s[t] += s[t + off];
        __syncthreads();
    }
    if (t == 0) part[blockIdx.x] = s[0];
}

// ---------------- scan the 196 partials (exclusive) ----------------
__global__ __launch_bounds__(SCAN_B) void k_scanpart(int* __restrict__ part) {
    __shared__ int s[SCAN_B];
    int t = threadIdx.x;
    int v = (t < NBLK) ? part[t] : 0;
    s[t] = v;
    __syncthreads();
    for (int off = 1; off < SCAN_B; off <<= 1) {
        int u = (t >= off) ? s[t - off] : 0;
        __syncthreads();
        s[t] += u;
        __syncthreads();
    }
    if (t < NBLK) part[t] = s[t] - v;  // exclusive prefix of block sums
}

// ---------------- per-block scan + offset -> rowstart/fillpos ----------------
__global__ __launch_bounds__(SCAN_B) void k_rowfill(const int* __restrict__ deg,
                                                    const int* __restrict__ part,
                                                    int* __restrict__ rowstart,
                                                    int* __restrict__ fillpos) {
    __shared__ int s[SCAN_B];
    int t = threadIdx.x;
    int i = blockIdx.x * SCAN_B + t;
    int v = (i < N) ? deg[i] : 0;
    s[t] = v;
    __syncthreads();
    for (int off = 1; off < SCAN_B; off <<= 1) {
        int u = (t >= off) ? s[t - off] : 0;
        __syncthreads();
        s[t] += u;
        __syncthreads();
    }
    int excl = s[t] - v + part[blockIdx.x];
    if (i < N) {
        rowstart[i] = excl;
        fillpos[i] = excl;
    }
    if (blockIdx.x == 0 && t == 0) rowstart[N] = E;  // total degree == E
}

// ---------------- CSR fill + per-edge coefficient ----------------
__global__ void k_fill(const int* __restrict__ src, const int* __restrict__ dst,
                       int* __restrict__ fillpos, const float* __restrict__ dinv,
                       int* __restrict__ csr_src, float* __restrict__ csr_coef) {
    int e = blockIdx.x * blockDim.x + threadIdx.x;
    if (e >= E) return;
    int d = dst[e], s = src[e];
    int pos = atomicAdd(&fillpos[d], 1);
    csr_src[pos] = s;
    csr_coef[pos] = dinv[s] * dinv[d];
}

// ---------------- C[N,128] = A[N,128] @ W[128,128]  (fp32, tiled) ----------------
__global__ __launch_bounds__(256) void k_gemm(const float* __restrict__ A,
                                              const float* __restrict__ W,
                                              float* __restrict__ C) {
    // A^T tile in LDS: [k][row], leading dim 68 (pad 4 keeps 16B align, breaks bank stride)
    __shared__ __align__(16) float Alds[128 * 68];
    int tid = threadIdx.x;
    int row0 = blockIdx.x * 64;

    for (int f = tid; f < 64 * 32; f += 256) {   // 2048 float4 elements
        int r = f >> 5;        // row within tile 0..63
        int kq = f & 31;       // float4 index along K
        int row = row0 + r;
        float4 v = make_float4(0.f, 0.f, 0.f, 0.f);
        if (row < N) v = ((const float4*)A)[row * 32 + kq];
        Alds[(4 * kq + 0) * 68 + r] = v.x;
        Alds[(4 * kq + 1) * 68 + r] = v.y;
        Alds[(4 * kq + 2) * 68 + r] = v.z;
        Alds[(4 * kq + 3) * 68 + r] = v.w;
    }
    __syncthreads();

    int tx = tid & 31;   // col group: cols 4*tx..4*tx+3
    int ty = tid >> 5;   // row group: rows 8*ty..8*ty+7
    float acc[8][4];
#pragma unroll
    for (int r = 0; r < 8; ++r)
#pragma unroll
        for (int c = 0; c < 4; ++c) acc[r][c] = 0.f;

    const float4* W4 = (const float4*)W;
#pragma unroll 4
    for (int k = 0; k < 128; ++k) {
        float4 w = W4[k * 32 + tx];
        const float4* ap = (const float4*)&Alds[k * 68 + 8 * ty];
        float4 a0 = ap[0], a1 = ap[1];
        float a[8] = {a0.x, a0.y, a0.z, a0.w, a1.x, a1.y, a1.z, a1.w};
#pragma unroll
        for (int r = 0; r < 8; ++r) {
            acc[r][0] = fmaf(a[r], w.x, acc[r][0]);
            acc[r][1] = fmaf(a[r], w.y, acc[r][1]);
            acc[r][2] = fmaf(a[r], w.z, acc[r][2]);
            acc[r][3] = fmaf(a[r], w.w, acc[r][3]);
        }
    }
#pragma unroll
    for (int r = 0; r < 8; ++r) {
        int row = row0 + 8 * ty + r;
        if (row < N) {
            float4 o = make_float4(acc[r][0], acc[r][1], acc[r][2], acc[r][3]);
            ((float4*)C)[row * 32 + tx] = o;
        }
    }
}

// ---------------- gather aggregation + bias + relu ----------------
__global__ __launch_bounds__(256) void k_agg(const float* __restrict__ tmp,
                                             const int* __restrict__ csr_src,
                                             const float* __restrict__ csr_coef,
                                             const int* __restrict__ rowstart,
                                             const float* __restrict__ dinv,
                                             const float* __restrict__ bias,
                                             float* __restrict__ out) {
    int node = (blockIdx.x * blockDim.x + threadIdx.x) >> 5;
    int lane = threadIdx.x & 31;
    if (node >= N) return;
    const float4* t4 = (const float4*)tmp;
    float di = dinv[node];
    float c0 = di * di;                       // self-loop coefficient
    float4 v = t4[node * 32 + lane];
    float4 acc = make_float4(v.x * c0, v.y * c0, v.z * c0, v.w * c0);
    int jb = rowstart[node], je = rowstart[node + 1];
    for (int j = jb; j < je; ++j) {
        int s = csr_src[j];
        float c = csr_coef[j];
        float4 u = t4[s * 32 + lane];
        acc.x = fmaf(u.x, c, acc.x);
        acc.y = fmaf(u.y, c, acc.y);
        acc.z = fmaf(u.z, c, acc.z);
        acc.w = fmaf(u.w, c, acc.w);
    }
    float4 b = ((const float4*)bias)[lane];
    float4 o;
    o.x = fmaxf(acc.x + b.x, 0.f);
    o.y = fmaxf(acc.y + b.y, 0.f);
    o.z = fmaxf(acc.z + b.z, 0.f);
    o.w = fmaxf(acc.w + b.w, 0.f);
    ((float4*)out)[node * 32 + lane] = o;
}

// ---------------- mean-pool accumulate (batch is sorted) ----------------
__global__ void k_pool(const float* __restrict__ h, const int* __restrict__ batch,
                       float* __restrict__ sums) {
    int grp = (blockIdx.x * blockDim.x + threadIdx.x) >> 5;
    int lane = threadIdx.x & 31;
    int base = grp * 64;
    if (base >= N) return;
    int end = (base + 64 < N) ? base + 64 : N;
    float4 acc = make_float4(0.f, 0.f, 0.f, 0.f);
    const float4* h4 = (const float4*)h;
    int curb = batch[base];
    for (int i = base; i < end; ++i) {
        int b = batch[i];
        if (b != curb) {
            float* sp = &sums[curb * F + lane * 4];
            atomicAdd(sp + 0, acc.x); atomicAdd(sp + 1, acc.y);
            atomicAdd(sp + 2, acc.z); atomicAdd(sp + 3, acc.w);
            acc = make_float4(0.f, 0.f, 0.f, 0.f);
            curb = b;
        }
        float4 v = h4[i * 32 + lane];
        acc.x += v.x; acc.y += v.y; acc.z += v.z; acc.w += v.w;
    }
    float* sp = &sums[curb * F + lane * 4];
    atomicAdd(sp + 0, acc.x); atomicAdd(sp + 1, acc.y);
    atomicAdd(sp + 2, acc.z); atomicAdd(sp + 3, acc.w);
}

__global__ void k_cnt(const int* __restrict__ batch, float* __restrict__ cnt) {
    int i = blockIdx.x * blockDim.x + threadIdx.x;
    if (i < N) atomicAdd(&cnt[batch[i]], 1.0f);
}

// ---------------- z = relu(pooled @ Wfc + bfc) ----------------
__global__ __launch_bounds__(128) void k_fc(const float* __restrict__ sums,
                                            const float* __restrict__ cnt,
                                            const float* __restrict__ Wfc,
                                            const float* __restrict__ bfc,
                                            float* __restrict__ z) {
    __shared__ float p[128];
    int g = blockIdx.x, t = threadIdx.x;
    float inv = 1.0f / fmaxf(cnt[g], 1.0f);
    p[t] = sums[g * F + t] * inv;
    __syncthreads();
    float acc = bfc[t];
    for (int k = 0; k < F; ++k) acc = fmaf(p[k], Wfc[k * F + t], acc);
    z[g * F + t] = fmaxf(acc, 0.f);
}

// ---------------- out[t,g,c] = z[g,:] . Wh[t,:,c] + bh[t,c] ----------------
__global__ void k_head(const float* __restrict__ z, const float* __restrict__ Wh,
                       const float* __restrict__ bh, float* __restrict__ out) {
    int o = blockIdx.x * blockDim.x + threadIdx.x;
    if (o >= T * G * 2) return;
    int tt = o >> 9;        // / (G*2)
    int rem = o & 511;
    int g = rem >> 1;
    int c = rem & 1;
    float acc = bh[tt * 2 + c];
    const float* zr = &z[g * F];
    const float* wr = &Wh[tt * F * 2 + c];
    for (int h = 0; h < F; ++h) acc = fmaf(zr[h], wr[h * 2], acc);
    out[o] = acc;
}

extern "C" void kernel_launch(void* const* d_in, const int* in_sizes, int n_in,
                              void* d_out, int out_size, void* d_ws, size_t ws_size,
                              hipStream_t stream) {
    const float* x    = (const float*)d_in[0];
    const int*   ei   = (const int*)d_in[1];      // [2,E]: row0=src, row1=dst
    const int*   batch= (const int*)d_in[2];
    const float* W1   = (const float*)d_in[3];
    const float* b1   = (const float*)d_in[4];
    const float* W2   = (const float*)d_in[5];
    const float* b2   = (const float*)d_in[6];
    const float* Wfc  = (const float*)d_in[7];
    const float* bfc  = (const float*)d_in[8];
    const float* Wh   = (const float*)d_in[9];
    const float* bh   = (const float*)d_in[10];
    float* out = (float*)d_out;

    const int* srcp = ei;
    const int* dstp = ei + E;

    char* w = (char*)d_ws;
    auto alloc = [&](size_t bytes) {
        char* p = w;
        w += (bytes + 255) & ~(size_t)255;
        return p;
    };
    float* tmp      = (float*)alloc((size_t)N * F * 4);
    float* hbuf     = (float*)alloc((size_t)N * F * 4);
    int*   csr_src  = (int*)  alloc((size_t)E * 4);
    float* csr_coef = (float*)alloc((size_t)E * 4);
    int*   rowstart = (int*)  alloc((size_t)(N + 1) * 4);
    int*   fillpos  = (int*)  alloc((size_t)N * 4);
    int*   deg      = (int*)  alloc((size_t)N * 4);
    float* dinv     = (float*)alloc((size_t)N * 4);
    int*   part     = (int*)  alloc((size_t)NBLK * 4);
    float* sums     = (float*)alloc((size_t)G * F * 4);
    float* cnt      = (float*)alloc((size_t)G * 4);
    float* z        = (float*)alloc((size_t)G * F * 4);

    hipMemsetAsync(deg, 0, (size_t)N * 4, stream);
    hipMemsetAsync(sums, 0, (size_t)G * F * 4, stream);
    hipMemsetAsync(cnt, 0, (size_t)G * 4, stream);

    // CSR build (two-level parallel scan)
    k_deg<<<(E + 255) / 256, 256, 0, stream>>>(dstp, deg);
    k_part<<<NBLK, SCAN_B, 0, stream>>>(deg, part, dinv);
    k_scanpart<<<1, SCAN_B, 0, stream>>>(part);
    k_rowfill<<<NBLK, SCAN_B, 0, stream>>>(deg, part, rowstart, fillpos);
    k_fill<<<(E + 255) / 256, 256, 0, stream>>>(srcp, dstp, fillpos, dinv, csr_src, csr_coef);

    // layer 1
    k_gemm<<<(N + 63) / 64, 256, 0, stream>>>(x, W1, tmp);
    k_agg<<<(N * 32 + 255) / 256, 256, 0, stream>>>(tmp, csr_src, csr_coef, rowstart, dinv, b1, hbuf);
    // layer 2
    k_gemm<<<(N + 63) / 64, 256, 0, stream>>>(hbuf, W2, tmp);
    k_agg<<<(N * 32 + 255) / 256, 256, 0, stream>>>(tmp, csr_src, csr_coef, rowstart, dinv, b2, hbuf);

    // pooling
    int ngrp = (N + 63) / 64;
    k_pool<<<(ngrp * 32 + 255) / 256, 256, 0, stream>>>(hbuf, batch, sums);
    k_cnt<<<(N + 255) / 256, 256, 0, stream>>>(batch, cnt);

    // fc + heads
    k_fc<<<G, 128, 0, stream>>>(sums, cnt, Wfc, bfc, z);
    k_head<<<(T * G * 2 + 255) / 256, 256, 0, stream>>>(z, Wh, bh, out);
}

// Round 3
// 431.977 us; speedup vs baseline: 1.4357x; 1.1488x over previous
//
#include <hip/hip_runtime.h>
#include <math.h>

constexpr int N = 50000;   // nodes
constexpr int E = 800000;  // edges (without self-loops)
constexpr int F = 128;     // features / hidden
constexpr int G = 256;     // graphs
constexpr int T = 4;       // tasks

constexpr int SCAN_B = 256;
constexpr int NBLK = (N + SCAN_B - 1) / SCAN_B;  // 196

// ---------------- degree histogram ----------------
__global__ void k_deg(const int* __restrict__ dst, int* __restrict__ deg) {
    int e = blockIdx.x * blockDim.x + threadIdx.x;
    if (e < E) atomicAdd(&deg[dst[e]], 1);
}

// ---------------- two-level scan: block partials + dinv ----------------
__global__ __launch_bounds__(SCAN_B) void k_part(const int* __restrict__ deg,
                                                 int* __restrict__ part,
                                                 float* __restrict__ dinv) {
    __shared__ int s[SCAN_B];
    int t = threadIdx.x;
    int i = blockIdx.x * SCAN_B + t;
    int v = (i < N) ? deg[i] : 0;
    if (i < N) dinv[i] = rsqrtf((float)(v + 1));  // +1 self-loop
    s[t] = v;
    __syncthreads();
#pragma unroll
    for (int off = SCAN_B / 2; off > 0; off >>= 1) {
        if (t < off) s[t] += s[t + off];
        __syncthreads();
    }
    if (t == 0) part[blockIdx.x] = s[0];
}

// ---------------- scan the 196 partials (exclusive) ----------------
__global__ __launch_bounds__(SCAN_B) void k_scanpart(int* __restrict__ part) {
    __shared__ int s[SCAN_B];
    int t = threadIdx.x;
    int v = (t < NBLK) ? part[t] : 0;
    s[t] = v;
    __syncthreads();
    for (int off = 1; off < SCAN_B; off <<= 1) {
        int u = (t >= off) ? s[t - off] : 0;
        __syncthreads();
        s[t] += u;
        __syncthreads();
    }
    if (t < NBLK) part[t] = s[t] - v;  // exclusive prefix of block sums
}

// ---------------- per-block scan + offset -> rowstart/fillpos ----------------
__global__ __launch_bounds__(SCAN_B) void k_rowfill(const int* __restrict__ deg,
                                                    const int* __restrict__ part,
                                                    int* __restrict__ rowstart,
                                                    int* __restrict__ fillpos) {
    __shared__ int s[SCAN_B];
    int t = threadIdx.x;
    int i = blockIdx.x * SCAN_B + t;
    int v = (i < N) ? deg[i] : 0;
    s[t] = v;
    __syncthreads();
    for (int off = 1; off < SCAN_B; off <<= 1) {
        int u = (t >= off) ? s[t - off] : 0;
        __syncthreads();
        s[t] += u;
        __syncthreads();
    }
    int excl = s[t] - v + part[blockIdx.x];
    if (i < N) {
        rowstart[i] = excl;
        fillpos[i] = excl;
    }
    if (blockIdx.x == 0 && t == 0) rowstart[N] = E;  // total degree == E
}

// ---------------- CSR fill + per-edge coefficient ----------------
__global__ void k_fill(const int* __restrict__ src, const int* __restrict__ dst,
                       int* __restrict__ fillpos, const float* __restrict__ dinv,
                       int* __restrict__ csr_src, float* __restrict__ csr_coef) {
    int e = blockIdx.x * blockDim.x + threadIdx.x;
    if (e >= E) return;
    int d = dst[e], s = src[e];
    int pos = atomicAdd(&fillpos[d], 1);
    csr_src[pos] = s;
    csr_coef[pos] = dinv[s] * dinv[d];
}

// ---------------- C[N,128] = A[N,128] @ W[128,128]  (fp32, tiled) ----------------
__global__ __launch_bounds__(256) void k_gemm(const float* __restrict__ A,
                                              const float* __restrict__ W,
                                              float* __restrict__ C) {
    // A^T tile in LDS: [k][row], leading dim 68 (pad 4 keeps 16B align, breaks bank stride)
    __shared__ __align__(16) float Alds[128 * 68];
    int tid = threadIdx.x;
    int row0 = blockIdx.x * 64;

    for (int f = tid; f < 64 * 32; f += 256) {   // 2048 float4 elements
        int r = f >> 5;        // row within tile 0..63
        int kq = f & 31;       // float4 index along K
        int row = row0 + r;
        float4 v = make_float4(0.f, 0.f, 0.f, 0.f);
        if (row < N) v = ((const float4*)A)[row * 32 + kq];
        Alds[(4 * kq + 0) * 68 + r] = v.x;
        Alds[(4 * kq + 1) * 68 + r] = v.y;
        Alds[(4 * kq + 2) * 68 + r] = v.z;
        Alds[(4 * kq + 3) * 68 + r] = v.w;
    }
    __syncthreads();

    int tx = tid & 31;   // col group: cols 4*tx..4*tx+3
    int ty = tid >> 5;   // row group: rows 8*ty..8*ty+7
    float acc[8][4];
#pragma unroll
    for (int r = 0; r < 8; ++r)
#pragma unroll
        for (int c = 0; c < 4; ++c) acc[r][c] = 0.f;

    const float4* W4 = (const float4*)W;
#pragma unroll 4
    for (int k = 0; k < 128; ++k) {
        float4 w = W4[k * 32 + tx];
        const float4* ap = (const float4*)&Alds[k * 68 + 8 * ty];
        float4 a0 = ap[0], a1 = ap[1];
        float a[8] = {a0.x, a0.y, a0.z, a0.w, a1.x, a1.y, a1.z, a1.w};
#pragma unroll
        for (int r = 0; r < 8; ++r) {
            acc[r][0] = fmaf(a[r], w.x, acc[r][0]);
            acc[r][1] = fmaf(a[r], w.y, acc[r][1]);
            acc[r][2] = fmaf(a[r], w.z, acc[r][2]);
            acc[r][3] = fmaf(a[r], w.w, acc[r][3]);
        }
    }
#pragma unroll
    for (int r = 0; r < 8; ++r) {
        int row = row0 + 8 * ty + r;
        if (row < N) {
            float4 o = make_float4(acc[r][0], acc[r][1], acc[r][2], acc[r][3]);
            ((float4*)C)[row * 32 + tx] = o;
        }
    }
}

// ---------------- gather aggregation + bias + relu ----------------
__global__ __launch_bounds__(256) void k_agg(const float* __restrict__ tmp,
                                             const int* __restrict__ csr_src,
                                             const float* __restrict__ csr_coef,
                                             const int* __restrict__ rowstart,
                                             const float* __restrict__ dinv,
                                             const float* __restrict__ bias,
                                             float* __restrict__ out) {
    int node = (blockIdx.x * blockDim.x + threadIdx.x) >> 5;
    int lane = threadIdx.x & 31;
    if (node >= N) return;
    const float4* t4 = (const float4*)tmp;
    float di = dinv[node];
    float c0 = di * di;                       // self-loop coefficient
    float4 v = t4[node * 32 + lane];
    float4 acc = make_float4(v.x * c0, v.y * c0, v.z * c0, v.w * c0);
    int jb = rowstart[node], je = rowstart[node + 1];
    for (int j = jb; j < je; ++j) {
        int s = csr_src[j];
        float c = csr_coef[j];
        float4 u = t4[s * 32 + lane];
        acc.x = fmaf(u.x, c, acc.x);
        acc.y = fmaf(u.y, c, acc.y);
        acc.z = fmaf(u.z, c, acc.z);
        acc.w = fmaf(u.w, c, acc.w);
    }
    float4 b = ((const float4*)bias)[lane];
    float4 o;
    o.x = fmaxf(acc.x + b.x, 0.f);
    o.y = fmaxf(acc.y + b.y, 0.f);
    o.z = fmaxf(acc.z + b.z, 0.f);
    o.w = fmaxf(acc.w + b.w, 0.f);
    ((float4*)out)[node * 32 + lane] = o;
}

// ---------------- mean-pool accumulate (batch is sorted) ----------------
__global__ void k_pool(const float* __restrict__ h, const int* __restrict__ batch,
                       float* __restrict__ sums) {
    int grp = (blockIdx.x * blockDim.x + threadIdx.x) >> 5;
    int lane = threadIdx.x & 31;
    int base = grp * 64;
    if (base >= N) return;
    int end = (base + 64 < N) ? base + 64 : N;
    float4 acc = make_float4(0.f, 0.f, 0.f, 0.f);
    const float4* h4 = (const float4*)h;
    int curb = batch[base];
    for (int i = base; i < end; ++i) {
        int b = batch[i];
        if (b != curb) {
            float* sp = &sums[curb * F + lane * 4];
            atomicAdd(sp + 0, acc.x); atomicAdd(sp + 1, acc.y);
            atomicAdd(sp + 2, acc.z); atomicAdd(sp + 3, acc.w);
            acc = make_float4(0.f, 0.f, 0.f, 0.f);
            curb = b;
        }
        float4 v = h4[i * 32 + lane];
        acc.x += v.x; acc.y += v.y; acc.z += v.z; acc.w += v.w;
    }
    float* sp = &sums[curb * F + lane * 4];
    atomicAdd(sp + 0, acc.x); atomicAdd(sp + 1, acc.y);
    atomicAdd(sp + 2, acc.z); atomicAdd(sp + 3, acc.w);
}

// ---------------- graph sizes via binary search over sorted batch ----------------
__global__ void k_cntbs(const int* __restrict__ batch, float* __restrict__ cnt) {
    int g = blockIdx.x * blockDim.x + threadIdx.x;
    if (g >= G) return;
    int lo0 = 0, hi0 = N;                 // lower_bound(g)
    while (lo0 < hi0) {
        int mid = (lo0 + hi0) >> 1;
        if (batch[mid] < g) lo0 = mid + 1; else hi0 = mid;
    }
    int lo1 = lo0, hi1 = N;               // lower_bound(g+1)
    while (lo1 < hi1) {
        int mid = (lo1 + hi1) >> 1;
        if (batch[mid] < g + 1) lo1 = mid + 1; else hi1 = mid;
    }
    cnt[g] = (float)(lo1 - lo0);
}

// ---------------- z = relu(pooled @ Wfc + bfc) ----------------
__global__ __launch_bounds__(128) void k_fc(const float* __restrict__ sums,
                                            const float* __restrict__ cnt,
                                            const float* __restrict__ Wfc,
                                            const float* __restrict__ bfc,
                                            float* __restrict__ z) {
    __shared__ float p[128];
    int g = blockIdx.x, t = threadIdx.x;
    float inv = 1.0f / fmaxf(cnt[g], 1.0f);
    p[t] = sums[g * F + t] * inv;
    __syncthreads();
    float acc = bfc[t];
    for (int k = 0; k < F; ++k) acc = fmaf(p[k], Wfc[k * F + t], acc);
    z[g * F + t] = fmaxf(acc, 0.f);
}

// ---------------- out[t,g,c] = z[g,:] . Wh[t,:,c] + bh[t,c] ----------------
__global__ void k_head(const float* __restrict__ z, const float* __restrict__ Wh,
                       const float* __restrict__ bh, float* __restrict__ out) {
    int o = blockIdx.x * blockDim.x + threadIdx.x;
    if (o >= T * G * 2) return;
    int tt = o >> 9;        // / (G*2)
    int rem = o & 511;
    int g = rem >> 1;
    int c = rem & 1;
    float acc = bh[tt * 2 + c];
    const float* zr = &z[g * F];
    const float* wr = &Wh[tt * F * 2 + c];
    for (int h = 0; h < F; ++h) acc = fmaf(zr[h], wr[h * 2], acc);
    out[o] = acc;
}

extern "C" void kernel_launch(void* const* d_in, const int* in_sizes, int n_in,
                              void* d_out, int out_size, void* d_ws, size_t ws_size,
                              hipStream_t stream) {
    const float* x    = (const float*)d_in[0];
    const int*   ei   = (const int*)d_in[1];      // [2,E]: row0=src, row1=dst
    const int*   batch= (const int*)d_in[2];
    const float* W1   = (const float*)d_in[3];
    const float* b1   = (const float*)d_in[4];
    const float* W2   = (const float*)d_in[5];
    const float* b2   = (const float*)d_in[6];
    const float* Wfc  = (const float*)d_in[7];
    const float* bfc  = (const float*)d_in[8];
    const float* Wh   = (const float*)d_in[9];
    const float* bh   = (const float*)d_in[10];
    float* out = (float*)d_out;

    const int* srcp = ei;
    const int* dstp = ei + E;

    char* w = (char*)d_ws;
    auto alloc = [&](size_t bytes) {
        char* p = w;
        w += (bytes + 255) & ~(size_t)255;
        return p;
    };
    float* tmp      = (float*)alloc((size_t)N * F * 4);
    float* hbuf     = (float*)alloc((size_t)N * F * 4);
    int*   csr_src  = (int*)  alloc((size_t)E * 4);
    float* csr_coef = (float*)alloc((size_t)E * 4);
    int*   rowstart = (int*)  alloc((size_t)(N + 1) * 4);
    int*   fillpos  = (int*)  alloc((size_t)N * 4);
    int*   deg      = (int*)  alloc((size_t)N * 4);
    float* dinv     = (float*)alloc((size_t)N * 4);
    int*   part     = (int*)  alloc((size_t)NBLK * 4);
    float* sums     = (float*)alloc((size_t)G * F * 4);
    float* cnt      = (float*)alloc((size_t)G * 4);
    float* z        = (float*)alloc((size_t)G * F * 4);

    hipMemsetAsync(deg, 0, (size_t)N * 4, stream);
    hipMemsetAsync(sums, 0, (size_t)G * F * 4, stream);

    // CSR build (two-level parallel scan)
    k_deg<<<(E + 255) / 256, 256, 0, stream>>>(dstp, deg);
    k_part<<<NBLK, SCAN_B, 0, stream>>>(deg, part, dinv);
    k_scanpart<<<1, SCAN_B, 0, stream>>>(part);
    k_rowfill<<<NBLK, SCAN_B, 0, stream>>>(deg, part, rowstart, fillpos);
    k_fill<<<(E + 255) / 256, 256, 0, stream>>>(srcp, dstp, fillpos, dinv, csr_src, csr_coef);

    // layer 1
    k_gemm<<<(N + 63) / 64, 256, 0, stream>>>(x, W1, tmp);
    k_agg<<<(N * 32 + 255) / 256, 256, 0, stream>>>(tmp, csr_src, csr_coef, rowstart, dinv, b1, hbuf);
    // layer 2
    k_gemm<<<(N + 63) / 64, 256, 0, stream>>>(hbuf, W2, tmp);
    k_agg<<<(N * 32 + 255) / 256, 256, 0, stream>>>(tmp, csr_src, csr_coef, rowstart, dinv, b2, hbuf);

    // pooling
    int ngrp = (N + 63) / 64;
    k_pool<<<(ngrp * 32 + 255) / 256, 256, 0, stream>>>(hbuf, batch, sums);
    k_cntbs<<<1, G, 0, stream>>>(batch, cnt);

    // fc + heads
    k_fc<<<G, 128, 0, stream>>>(sums, cnt, Wfc, bfc, z);
    k_head<<<(T * G * 2 + 255) / 256, 256, 0, stream>>>(z, Wh, bh, out);
}

// Round 4
// 391.764 us; speedup vs baseline: 1.5831x; 1.1026x over previous
//
#include <hip/hip_runtime.h>
#include <math.h>

constexpr int N = 50000;   // nodes
constexpr int E = 800000;  // edges (without self-loops)
constexpr int F = 128;     // features / hidden
constexpr int G = 256;     // graphs
constexpr int T = 4;       // tasks

constexpr int SCAN_B = 256;
constexpr int NBLK = (N + SCAN_B - 1) / SCAN_B;  // 196

// bf16 <-> fp32 helpers (RNE on pack; values are finite)
__device__ inline float bf2f(unsigned short u) {
    union { unsigned int i; float f; } v;
    v.i = ((unsigned int)u) << 16;
    return v.f;
}
__device__ inline unsigned short f2bf(float f) {
    union { float f; unsigned int i; } v;
    v.f = f;
    unsigned int r = v.i + 0x7FFF + ((v.i >> 16) & 1);
    return (unsigned short)(r >> 16);
}

// ---------------- degree histogram ----------------
__global__ void k_deg(const int* __restrict__ dst, int* __restrict__ deg) {
    int e = blockIdx.x * blockDim.x + threadIdx.x;
    if (e < E) atomicAdd(&deg[dst[e]], 1);
}

// ---------------- two-level scan: block partials + dinv ----------------
__global__ __launch_bounds__(SCAN_B) void k_part(const int* __restrict__ deg,
                                                 int* __restrict__ part,
                                                 float* __restrict__ dinv) {
    __shared__ int s[SCAN_B];
    int t = threadIdx.x;
    int i = blockIdx.x * SCAN_B + t;
    int v = (i < N) ? deg[i] : 0;
    if (i < N) dinv[i] = rsqrtf((float)(v + 1));  // +1 self-loop
    s[t] = v;
    __syncthreads();
#pragma unroll
    for (int off = SCAN_B / 2; off > 0; off >>= 1) {
        if (t < off) s[t] += s[t + off];
        __syncthreads();
    }
    if (t == 0) part[blockIdx.x] = s[0];
}

// ---------------- scan the 196 partials (exclusive) ----------------
__global__ __launch_bounds__(SCAN_B) void k_scanpart(int* __restrict__ part) {
    __shared__ int s[SCAN_B];
    int t = threadIdx.x;
    int v = (t < NBLK) ? part[t] : 0;
    s[t] = v;
    __syncthreads();
    for (int off = 1; off < SCAN_B; off <<= 1) {
        int u = (t >= off) ? s[t - off] : 0;
        __syncthreads();
        s[t] += u;
        __syncthreads();
    }
    if (t < NBLK) part[t] = s[t] - v;  // exclusive prefix of block sums
}

// ---------------- per-block scan + offset -> rowstart/fillpos ----------------
__global__ __launch_bounds__(SCAN_B) void k_rowfill(const int* __restrict__ deg,
                                                    const int* __restrict__ part,
                                                    int* __restrict__ rowstart,
                                                    int* __restrict__ fillpos) {
    __shared__ int s[SCAN_B];
    int t = threadIdx.x;
    int i = blockIdx.x * SCAN_B + t;
    int v = (i < N) ? deg[i] : 0;
    s[t] = v;
    __syncthreads();
    for (int off = 1; off < SCAN_B; off <<= 1) {
        int u = (t >= off) ? s[t - off] : 0;
        __syncthreads();
        s[t] += u;
        __syncthreads();
    }
    int excl = s[t] - v + part[blockIdx.x];
    if (i < N) {
        rowstart[i] = excl;
        fillpos[i] = excl;
    }
    if (blockIdx.x == 0 && t == 0) rowstart[N] = E;  // total degree == E
}

// ---------------- CSR fill + per-edge coefficient ----------------
__global__ void k_fill(const int* __restrict__ src, const int* __restrict__ dst,
                       int* __restrict__ fillpos, const float* __restrict__ dinv,
                       int* __restrict__ csr_src, float* __restrict__ csr_coef) {
    int e = blockIdx.x * blockDim.x + threadIdx.x;
    if (e >= E) return;
    int d = dst[e], s = src[e];
    int pos = atomicAdd(&fillpos[d], 1);
    csr_src[pos] = s;
    csr_coef[pos] = dinv[s] * dinv[d];
}

// ---------------- C16[N,128](bf16) = A[N,128] @ W[128,128]  (fp32 FMA) ----------------
__global__ __launch_bounds__(256) void k_gemm(const float* __restrict__ A,
                                              const float* __restrict__ W,
                                              unsigned short* __restrict__ C16) {
    // A^T tile in LDS: [k][row], leading dim 68 (pad 4 keeps 16B align, breaks bank stride)
    __shared__ __align__(16) float Alds[128 * 68];
    int tid = threadIdx.x;
    int row0 = blockIdx.x * 64;

    for (int f = tid; f < 64 * 32; f += 256) {   // 2048 float4 elements
        int r = f >> 5;        // row within tile 0..63
        int kq = f & 31;       // float4 index along K
        int row = row0 + r;
        float4 v = make_float4(0.f, 0.f, 0.f, 0.f);
        if (row < N) v = ((const float4*)A)[row * 32 + kq];
        Alds[(4 * kq + 0) * 68 + r] = v.x;
        Alds[(4 * kq + 1) * 68 + r] = v.y;
        Alds[(4 * kq + 2) * 68 + r] = v.z;
        Alds[(4 * kq + 3) * 68 + r] = v.w;
    }
    __syncthreads();

    int tx = tid & 31;   // col group: cols 4*tx..4*tx+3
    int ty = tid >> 5;   // row group: rows 8*ty..8*ty+7
    float acc[8][4];
#pragma unroll
    for (int r = 0; r < 8; ++r)
#pragma unroll
        for (int c = 0; c < 4; ++c) acc[r][c] = 0.f;

    const float4* W4 = (const float4*)W;
#pragma unroll 4
    for (int k = 0; k < 128; ++k) {
        float4 w = W4[k * 32 + tx];
        const float4* ap = (const float4*)&Alds[k * 68 + 8 * ty];
        float4 a0 = ap[0], a1 = ap[1];
        float a[8] = {a0.x, a0.y, a0.z, a0.w, a1.x, a1.y, a1.z, a1.w};
#pragma unroll
        for (int r = 0; r < 8; ++r) {
            acc[r][0] = fmaf(a[r], w.x, acc[r][0]);
            acc[r][1] = fmaf(a[r], w.y, acc[r][1]);
            acc[r][2] = fmaf(a[r], w.z, acc[r][2]);
            acc[r][3] = fmaf(a[r], w.w, acc[r][3]);
        }
    }
#pragma unroll
    for (int r = 0; r < 8; ++r) {
        int row = row0 + 8 * ty + r;
        if (row < N) {
            ushort4 o;
            o.x = f2bf(acc[r][0]);
            o.y = f2bf(acc[r][1]);
            o.z = f2bf(acc[r][2]);
            o.w = f2bf(acc[r][3]);
            ((ushort4*)C16)[row * 32 + tx] = o;
        }
    }
}

// ---------------- gather aggregation (bf16 messages) + bias + relu ----------------
__global__ __launch_bounds__(256) void k_agg(const unsigned short* __restrict__ tmp16,
                                             const int* __restrict__ csr_src,
                                             const float* __restrict__ csr_coef,
                                             const int* __restrict__ rowstart,
                                             const float* __restrict__ dinv,
                                             const float* __restrict__ bias,
                                             float* __restrict__ out) {
    int node = (blockIdx.x * blockDim.x + threadIdx.x) >> 5;
    int lane = threadIdx.x & 31;
    if (node >= N) return;
    const ushort4* t4 = (const ushort4*)tmp16;
    float di = dinv[node];
    float c0 = di * di;                       // self-loop coefficient
    ushort4 v = t4[node * 32 + lane];
    float4 acc = make_float4(bf2f(v.x) * c0, bf2f(v.y) * c0,
                             bf2f(v.z) * c0, bf2f(v.w) * c0);
    int jb = rowstart[node], je = rowstart[node + 1];
    for (int j = jb; j < je; ++j) {
        int s = csr_src[j];
        float c = csr_coef[j];
        ushort4 u = t4[s * 32 + lane];
        acc.x = fmaf(bf2f(u.x), c, acc.x);
        acc.y = fmaf(bf2f(u.y), c, acc.y);
        acc.z = fmaf(bf2f(u.z), c, acc.z);
        acc.w = fmaf(bf2f(u.w), c, acc.w);
    }
    float4 b = ((const float4*)bias)[lane];
    float4 o;
    o.x = fmaxf(acc.x + b.x, 0.f);
    o.y = fmaxf(acc.y + b.y, 0.f);
    o.z = fmaxf(acc.z + b.z, 0.f);
    o.w = fmaxf(acc.w + b.w, 0.f);
    ((float4*)out)[node * 32 + lane] = o;
}

// ---------------- mean-pool accumulate (batch is sorted) ----------------
__global__ void k_pool(const float* __restrict__ h, const int* __restrict__ batch,
                       float* __restrict__ sums) {
    int grp = (blockIdx.x * blockDim.x + threadIdx.x) >> 5;
    int lane = threadIdx.x & 31;
    int base = grp * 64;
    if (base >= N) return;
    int end = (base + 64 < N) ? base + 64 : N;
    float4 acc = make_float4(0.f, 0.f, 0.f, 0.f);
    const float4* h4 = (const float4*)h;
    int curb = batch[base];
    for (int i = base; i < end; ++i) {
        int b = batch[i];
        if (b != curb) {
            float* sp = &sums[curb * F + lane * 4];
            atomicAdd(sp + 0, acc.x); atomicAdd(sp + 1, acc.y);
            atomicAdd(sp + 2, acc.z); atomicAdd(sp + 3, acc.w);
            acc = make_float4(0.f, 0.f, 0.f, 0.f);
            curb = b;
        }
        float4 v = h4[i * 32 + lane];
        acc.x += v.x; acc.y += v.y; acc.z += v.z; acc.w += v.w;
    }
    float* sp = &sums[curb * F + lane * 4];
    atomicAdd(sp + 0, acc.x); atomicAdd(sp + 1, acc.y);
    atomicAdd(sp + 2, acc.z); atomicAdd(sp + 3, acc.w);
}

// ---------------- graph sizes via binary search over sorted batch ----------------
__global__ void k_cntbs(const int* __restrict__ batch, float* __restrict__ cnt) {
    int g = blockIdx.x * blockDim.x + threadIdx.x;
    if (g >= G) return;
    int lo0 = 0, hi0 = N;                 // lower_bound(g)
    while (lo0 < hi0) {
        int mid = (lo0 + hi0) >> 1;
        if (batch[mid] < g) lo0 = mid + 1; else hi0 = mid;
    }
    int lo1 = lo0, hi1 = N;               // lower_bound(g+1)
    while (lo1 < hi1) {
        int mid = (lo1 + hi1) >> 1;
        if (batch[mid] < g + 1) lo1 = mid + 1; else hi1 = mid;
    }
    cnt[g] = (float)(lo1 - lo0);
}

// ---------------- z = relu(pooled @ Wfc + bfc) ----------------
__global__ __launch_bounds__(128) void k_fc(const float* __restrict__ sums,
                                            const float* __restrict__ cnt,
                                            const float* __restrict__ Wfc,
                                            const float* __restrict__ bfc,
                                            float* __restrict__ z) {
    __shared__ float p[128];
    int g = blockIdx.x, t = threadIdx.x;
    float inv = 1.0f / fmaxf(cnt[g], 1.0f);
    p[t] = sums[g * F + t] * inv;
    __syncthreads();
    float acc = bfc[t];
    for (int k = 0; k < F; ++k) acc = fmaf(p[k], Wfc[k * F + t], acc);
    z[g * F + t] = fmaxf(acc, 0.f);
}

// ---------------- out[t,g,c] = z[g,:] . Wh[t,:,c] + bh[t,c] ----------------
__global__ void k_head(const float* __restrict__ z, const float* __restrict__ Wh,
                       const float* __restrict__ bh, float* __restrict__ out) {
    int o = blockIdx.x * blockDim.x + threadIdx.x;
    if (o >= T * G * 2) return;
    int tt = o >> 9;        // / (G*2)
    int rem = o & 511;
    int g = rem >> 1;
    int c = rem & 1;
    float acc = bh[tt * 2 + c];
    const float* zr = &z[g * F];
    const float* wr = &Wh[tt * F * 2 + c];
    for (int h = 0; h < F; ++h) acc = fmaf(zr[h], wr[h * 2], acc);
    out[o] = acc;
}

extern "C" void kernel_launch(void* const* d_in, const int* in_sizes, int n_in,
                              void* d_out, int out_size, void* d_ws, size_t ws_size,
                              hipStream_t stream) {
    const float* x    = (const float*)d_in[0];
    const int*   ei   = (const int*)d_in[1];      // [2,E]: row0=src, row1=dst
    const int*   batch= (const int*)d_in[2];
    const float* W1   = (const float*)d_in[3];
    const float* b1   = (const float*)d_in[4];
    const float* W2   = (const float*)d_in[5];
    const float* b2   = (const float*)d_in[6];
    const float* Wfc  = (const float*)d_in[7];
    const float* bfc  = (const float*)d_in[8];
    const float* Wh   = (const float*)d_in[9];
    const float* bh   = (const float*)d_in[10];
    float* out = (float*)d_out;

    const int* srcp = ei;
    const int* dstp = ei + E;

    char* w = (char*)d_ws;
    auto alloc = [&](size_t bytes) {
        char* p = w;
        w += (bytes + 255) & ~(size_t)255;
        return p;
    };
    unsigned short* tmp16 = (unsigned short*)alloc((size_t)N * F * 2);
    float* hbuf     = (float*)alloc((size_t)N * F * 4);
    int*   csr_src  = (int*)  alloc((size_t)E * 4);
    float* csr_coef = (float*)alloc((size_t)E * 4);
    int*   rowstart = (int*)  alloc((size_t)(N + 1) * 4);
    int*   fillpos  = (int*)  alloc((size_t)N * 4);
    int*   deg      = (int*)  alloc((size_t)N * 4);
    float* dinv     = (float*)alloc((size_t)N * 4);
    int*   part     = (int*)  alloc((size_t)NBLK * 4);
    float* sums     = (float*)alloc((size_t)G * F * 4);
    float* cnt      = (float*)alloc((size_t)G * 4);
    float* z        = (float*)alloc((size_t)G * F * 4);

    hipMemsetAsync(deg, 0, (size_t)N * 4, stream);
    hipMemsetAsync(sums, 0, (size_t)G * F * 4, stream);

    // CSR build (two-level parallel scan)
    k_deg<<<(E + 255) / 256, 256, 0, stream>>>(dstp, deg);
    k_part<<<NBLK, SCAN_B, 0, stream>>>(deg, part, dinv);
    k_scanpart<<<1, SCAN_B, 0, stream>>>(part);
    k_rowfill<<<NBLK, SCAN_B, 0, stream>>>(deg, part, rowstart, fillpos);
    k_fill<<<(E + 255) / 256, 256, 0, stream>>>(srcp, dstp, fillpos, dinv, csr_src, csr_coef);

    // layer 1
    k_gemm<<<(N + 63) / 64, 256, 0, stream>>>(x, W1, tmp16);
    k_agg<<<(N * 32 + 255) / 256, 256, 0, stream>>>(tmp16, csr_src, csr_coef, rowstart, dinv, b1, hbuf);
    // layer 2
    k_gemm<<<(N + 63) / 64, 256, 0, stream>>>(hbuf, W2, tmp16);
    k_agg<<<(N * 32 + 255) / 256, 256, 0, stream>>>(tmp16, csr_src, csr_coef, rowstart, dinv, b2, hbuf);

    // pooling
    int ngrp = (N + 63) / 64;
    k_pool<<<(ngrp * 32 + 255) / 256, 256, 0, stream>>>(hbuf, batch, sums);
    k_cntbs<<<1, G, 0, stream>>>(batch, cnt);

    // fc + heads
    k_fc<<<G, 128, 0, stream>>>(sums, cnt, Wfc, bfc, z);
    k_head<<<(T * G * 2 + 255) / 256, 256, 0, stream>>>(z, Wh, bh, out);
}

// Round 5
// 349.634 us; speedup vs baseline: 1.7739x; 1.1205x over previous
//
#include <hip/hip_runtime.h>
#include <math.h>

constexpr int N = 50000;   // nodes
constexpr int E = 800000;  // edges (without self-loops)
constexpr int F = 128;     // features / hidden
constexpr int G = 256;     // graphs
constexpr int T = 4;       // tasks

constexpr int SCAN_B = 256;
constexpr int NBLK = (N + SCAN_B - 1) / SCAN_B;  // 196

// bf16 <-> fp32 helpers (RNE on pack; values are finite)
__device__ inline float bf2f(unsigned short u) {
    union { unsigned int i; float f; } v;
    v.i = ((unsigned int)u) << 16;
    return v.f;
}
__device__ inline unsigned short f2bf(float f) {
    union { float f; unsigned int i; } v;
    v.f = f;
    unsigned int r = v.i + 0x7FFF + ((v.i >> 16) & 1);
    return (unsigned short)(r >> 16);
}

// ---------------- degree histogram ----------------
__global__ void k_deg(const int* __restrict__ dst, int* __restrict__ deg) {
    int e = blockIdx.x * blockDim.x + threadIdx.x;
    if (e < E) atomicAdd(&deg[dst[e]], 1);
}

// ---------------- two-level scan: block partials + dinv ----------------
__global__ __launch_bounds__(SCAN_B) void k_part(const int* __restrict__ deg,
                                                 int* __restrict__ part,
                                                 float* __restrict__ dinv) {
    __shared__ int s[SCAN_B];
    int t = threadIdx.x;
    int i = blockIdx.x * SCAN_B + t;
    int v = (i < N) ? deg[i] : 0;
    if (i < N) dinv[i] = rsqrtf((float)(v + 1));  // +1 self-loop
    s[t] = v;
    __syncthreads();
#pragma unroll
    for (int off = SCAN_B / 2; off > 0; off >>= 1) {
        if (t < off) s[t] += s[t + off];
        __syncthreads();
    }
    if (t == 0) part[blockIdx.x] = s[0];
}

// ---------------- scan the 196 partials (exclusive) ----------------
__global__ __launch_bounds__(SCAN_B) void k_scanpart(int* __restrict__ part) {
    __shared__ int s[SCAN_B];
    int t = threadIdx.x;
    int v = (t < NBLK) ? part[t] : 0;
    s[t] = v;
    __syncthreads();
    for (int off = 1; off < SCAN_B; off <<= 1) {
        int u = (t >= off) ? s[t - off] : 0;
        __syncthreads();
        s[t] += u;
        __syncthreads();
    }
    if (t < NBLK) part[t] = s[t] - v;  // exclusive prefix of block sums
}

// ---------------- per-block scan + offset -> rowstart/fillpos ----------------
__global__ __launch_bounds__(SCAN_B) void k_rowfill(const int* __restrict__ deg,
                                                    const int* __restrict__ part,
                                                    int* __restrict__ rowstart,
                                                    int* __restrict__ fillpos) {
    __shared__ int s[SCAN_B];
    int t = threadIdx.x;
    int i = blockIdx.x * SCAN_B + t;
    int v = (i < N) ? deg[i] : 0;
    s[t] = v;
    __syncthreads();
    for (int off = 1; off < SCAN_B; off <<= 1) {
        int u = (t >= off) ? s[t - off] : 0;
        __syncthreads();
        s[t] += u;
        __syncthreads();
    }
    int excl = s[t] - v + part[blockIdx.x];
    if (i < N) {
        rowstart[i] = excl;
        fillpos[i] = excl;
    }
    if (blockIdx.x == 0 && t == 0) rowstart[N] = E;  // total degree == E
}

// ---------------- CSR fill: packed {src, coef_bits} per edge ----------------
__global__ void k_fill(const int* __restrict__ src, const int* __restrict__ dst,
                       int* __restrict__ fillpos, const float* __restrict__ dinv,
                       int2* __restrict__ csr) {
    int e = blockIdx.x * blockDim.x + threadIdx.x;
    if (e >= E) return;
    int d = dst[e], s = src[e];
    int pos = atomicAdd(&fillpos[d], 1);
    float coef = dinv[s] * dinv[d];
    csr[pos] = make_int2(s, __float_as_int(coef));
}

// ---------------- C16[N,128](bf16) = A[N,128] @ W[128,128]  (fp32 FMA) ----------------
__global__ __launch_bounds__(256) void k_gemm(const float* __restrict__ A,
                                              const float* __restrict__ W,
                                              unsigned short* __restrict__ C16) {
    // A^T tile in LDS: [k][row], leading dim 68 (pad 4 keeps 16B align, breaks bank stride)
    __shared__ __align__(16) float Alds[128 * 68];
    int tid = threadIdx.x;
    int row0 = blockIdx.x * 64;

    for (int f = tid; f < 64 * 32; f += 256) {   // 2048 float4 elements
        int r = f >> 5;        // row within tile 0..63
        int kq = f & 31;       // float4 index along K
        int row = row0 + r;
        float4 v = make_float4(0.f, 0.f, 0.f, 0.f);
        if (row < N) v = ((const float4*)A)[row * 32 + kq];
        Alds[(4 * kq + 0) * 68 + r] = v.x;
        Alds[(4 * kq + 1) * 68 + r] = v.y;
        Alds[(4 * kq + 2) * 68 + r] = v.z;
        Alds[(4 * kq + 3) * 68 + r] = v.w;
    }
    __syncthreads();

    int tx = tid & 31;   // col group: cols 4*tx..4*tx+3
    int ty = tid >> 5;   // row group: rows 8*ty..8*ty+7
    float acc[8][4];
#pragma unroll
    for (int r = 0; r < 8; ++r)
#pragma unroll
        for (int c = 0; c < 4; ++c) acc[r][c] = 0.f;

    const float4* W4 = (const float4*)W;
#pragma unroll 4
    for (int k = 0; k < 128; ++k) {
        float4 w = W4[k * 32 + tx];
        const float4* ap = (const float4*)&Alds[k * 68 + 8 * ty];
        float4 a0 = ap[0], a1 = ap[1];
        float a[8] = {a0.x, a0.y, a0.z, a0.w, a1.x, a1.y, a1.z, a1.w};
#pragma unroll
        for (int r = 0; r < 8; ++r) {
            acc[r][0] = fmaf(a[r], w.x, acc[r][0]);
            acc[r][1] = fmaf(a[r], w.y, acc[r][1]);
            acc[r][2] = fmaf(a[r], w.z, acc[r][2]);
            acc[r][3] = fmaf(a[r], w.w, acc[r][3]);
        }
    }
#pragma unroll
    for (int r = 0; r < 8; ++r) {
        int row = row0 + 8 * ty + r;
        if (row < N) {
            ushort4 o;
            o.x = f2bf(acc[r][0]);
            o.y = f2bf(acc[r][1]);
            o.z = f2bf(acc[r][2]);
            o.w = f2bf(acc[r][3]);
            ((ushort4*)C16)[row * 32 + tx] = o;
        }
    }
}

// 8 bf16 (uint4) fma into 8 fp32 accumulators
__device__ inline void fma8(const uint4& u, float c, float* acc) {
    union { unsigned int i; float f; } a;
    a.i = u.x << 16;          acc[0] = fmaf(a.f, c, acc[0]);
    a.i = u.x & 0xFFFF0000u;  acc[1] = fmaf(a.f, c, acc[1]);
    a.i = u.y << 16;          acc[2] = fmaf(a.f, c, acc[2]);
    a.i = u.y & 0xFFFF0000u;  acc[3] = fmaf(a.f, c, acc[3]);
    a.i = u.z << 16;          acc[4] = fmaf(a.f, c, acc[4]);
    a.i = u.z & 0xFFFF0000u;  acc[5] = fmaf(a.f, c, acc[5]);
    a.i = u.w << 16;          acc[6] = fmaf(a.f, c, acc[6]);
    a.i = u.w & 0xFFFF0000u;  acc[7] = fmaf(a.f, c, acc[7]);
}

// ---------------- gather aggregation (bf16 msgs, 16 lanes/row, 4x unroll) ----------------
__global__ __launch_bounds__(256) void k_agg(const unsigned short* __restrict__ tmp16,
                                             const int2* __restrict__ csr,
                                             const int* __restrict__ rowstart,
                                             const float* __restrict__ dinv,
                                             const float* __restrict__ bias,
                                             float* __restrict__ out) {
    int node = (blockIdx.x * blockDim.x + threadIdx.x) >> 4;
    int lane = threadIdx.x & 15;           // 16 B per lane -> 256 B row
    if (node >= N) return;
    const uint4* t8 = (const uint4*)tmp16; // 16 uint4 per row
    float di = dinv[node];
    float c0 = di * di;                    // self-loop coefficient
    float acc[8] = {0.f, 0.f, 0.f, 0.f, 0.f, 0.f, 0.f, 0.f};
    fma8(t8[node * 16 + lane], c0, acc);

    int jb = rowstart[node], je = rowstart[node + 1];
    int j = jb;
    for (; j + 4 <= je; j += 4) {
        int2 e0 = csr[j + 0];
        int2 e1 = csr[j + 1];
        int2 e2 = csr[j + 2];
        int2 e3 = csr[j + 3];
        uint4 u0 = t8[e0.x * 16 + lane];   // 4 independent gathers in flight
        uint4 u1 = t8[e1.x * 16 + lane];
        uint4 u2 = t8[e2.x * 16 + lane];
        uint4 u3 = t8[e3.x * 16 + lane];
        fma8(u0, __int_as_float(e0.y), acc);
        fma8(u1, __int_as_float(e1.y), acc);
        fma8(u2, __int_as_float(e2.y), acc);
        fma8(u3, __int_as_float(e3.y), acc);
    }
    for (; j < je; ++j) {
        int2 e = csr[j];
        fma8(t8[e.x * 16 + lane], __int_as_float(e.y), acc);
    }

    const float4* b4 = (const float4*)bias;
    float4 ba = b4[lane * 2], bb = b4[lane * 2 + 1];
    float4 o0, o1;
    o0.x = fmaxf(acc[0] + ba.x, 0.f);
    o0.y = fmaxf(acc[1] + ba.y, 0.f);
    o0.z = fmaxf(acc[2] + ba.z, 0.f);
    o0.w = fmaxf(acc[3] + ba.w, 0.f);
    o1.x = fmaxf(acc[4] + bb.x, 0.f);
    o1.y = fmaxf(acc[5] + bb.y, 0.f);
    o1.z = fmaxf(acc[6] + bb.z, 0.f);
    o1.w = fmaxf(acc[7] + bb.w, 0.f);
    float4* o4 = (float4*)out;
    o4[node * 32 + lane * 2] = o0;
    o4[node * 32 + lane * 2 + 1] = o1;
}

// ---------------- mean-pool accumulate (batch is sorted) ----------------
__global__ void k_pool(const float* __restrict__ h, const int* __restrict__ batch,
                       float* __restrict__ sums) {
    int grp = (blockIdx.x * blockDim.x + threadIdx.x) >> 5;
    int lane = threadIdx.x & 31;
    int base = grp * 64;
    if (base >= N) return;
    int end = (base + 64 < N) ? base + 64 : N;
    float4 acc = make_float4(0.f, 0.f, 0.f, 0.f);
    const float4* h4 = (const float4*)h;
    int curb = batch[base];
    for (int i = base; i < end; ++i) {
        int b = batch[i];
        if (b != curb) {
            float* sp = &sums[curb * F + lane * 4];
            atomicAdd(sp + 0, acc.x); atomicAdd(sp + 1, acc.y);
            atomicAdd(sp + 2, acc.z); atomicAdd(sp + 3, acc.w);
            acc = make_float4(0.f, 0.f, 0.f, 0.f);
            curb = b;
        }
        float4 v = h4[i * 32 + lane];
        acc.x += v.x; acc.y += v.y; acc.z += v.z; acc.w += v.w;
    }
    float* sp = &sums[curb * F + lane * 4];
    atomicAdd(sp + 0, acc.x); atomicAdd(sp + 1, acc.y);
    atomicAdd(sp + 2, acc.z); atomicAdd(sp + 3, acc.w);
}

// ---------------- graph sizes via binary search over sorted batch ----------------
__global__ void k_cntbs(const int* __restrict__ batch, float* __restrict__ cnt) {
    int g = blockIdx.x * blockDim.x + threadIdx.x;
    if (g >= G) return;
    int lo0 = 0, hi0 = N;                 // lower_bound(g)
    while (lo0 < hi0) {
        int mid = (lo0 + hi0) >> 1;
        if (batch[mid] < g) lo0 = mid + 1; else hi0 = mid;
    }
    int lo1 = lo0, hi1 = N;               // lower_bound(g+1)
    while (lo1 < hi1) {
        int mid = (lo1 + hi1) >> 1;
        if (batch[mid] < g + 1) lo1 = mid + 1; else hi1 = mid;
    }
    cnt[g] = (float)(lo1 - lo0);
}

// ---------------- z = relu(pooled @ Wfc + bfc) ----------------
__global__ __launch_bounds__(128) void k_fc(const float* __restrict__ sums,
                                            const float* __restrict__ cnt,
                                            const float* __restrict__ Wfc,
                                            const float* __restrict__ bfc,
                                            float* __restrict__ z) {
    __shared__ float p[128];
    int g = blockIdx.x, t = threadIdx.x;
    float inv = 1.0f / fmaxf(cnt[g], 1.0f);
    p[t] = sums[g * F + t] * inv;
    __syncthreads();
    float acc = bfc[t];
    for (int k = 0; k < F; ++k) acc = fmaf(p[k], Wfc[k * F + t], acc);
    z[g * F + t] = fmaxf(acc, 0.f);
}

// ---------------- out[t,g,c] = z[g,:] . Wh[t,:,c] + bh[t,c] ----------------
__global__ void k_head(const float* __restrict__ z, const float* __restrict__ Wh,
                       const float* __restrict__ bh, float* __restrict__ out) {
    int o = blockIdx.x * blockDim.x + threadIdx.x;
    if (o >= T * G * 2) return;
    int tt = o >> 9;        // / (G*2)
    int rem = o & 511;
    int g = rem >> 1;
    int c = rem & 1;
    float acc = bh[tt * 2 + c];
    const float* zr = &z[g * F];
    const float* wr = &Wh[tt * F * 2 + c];
    for (int h = 0; h < F; ++h) acc = fmaf(zr[h], wr[h * 2], acc);
    out[o] = acc;
}

extern "C" void kernel_launch(void* const* d_in, const int* in_sizes, int n_in,
                              void* d_out, int out_size, void* d_ws, size_t ws_size,
                              hipStream_t stream) {
    const float* x    = (const float*)d_in[0];
    const int*   ei   = (const int*)d_in[1];      // [2,E]: row0=src, row1=dst
    const int*   batch= (const int*)d_in[2];
    const float* W1   = (const float*)d_in[3];
    const float* b1   = (const float*)d_in[4];
    const float* W2   = (const float*)d_in[5];
    const float* b2   = (const float*)d_in[6];
    const float* Wfc  = (const float*)d_in[7];
    const float* bfc  = (const float*)d_in[8];
    const float* Wh   = (const float*)d_in[9];
    const float* bh   = (const float*)d_in[10];
    float* out = (float*)d_out;

    const int* srcp = ei;
    const int* dstp = ei + E;

    char* w = (char*)d_ws;
    auto alloc = [&](size_t bytes) {
        char* p = w;
        w += (bytes + 255) & ~(size_t)255;
        return p;
    };
    unsigned short* tmp16 = (unsigned short*)alloc((size_t)N * F * 2);
    float* hbuf     = (float*)alloc((size_t)N * F * 4);
    int2*  csr      = (int2*) alloc((size_t)E * 8);
    int*   rowstart = (int*)  alloc((size_t)(N + 1) * 4);
    int*   fillpos  = (int*)  alloc((size_t)N * 4);
    int*   deg      = (int*)  alloc((size_t)N * 4);
    float* dinv     = (float*)alloc((size_t)N * 4);
    int*   part     = (int*)  alloc((size_t)NBLK * 4);
    float* sums     = (float*)alloc((size_t)G * F * 4);
    float* cnt      = (float*)alloc((size_t)G * 4);
    float* z        = (float*)alloc((size_t)G * F * 4);

    hipMemsetAsync(deg, 0, (size_t)N * 4, stream);
    hipMemsetAsync(sums, 0, (size_t)G * F * 4, stream);

    // CSR build (two-level parallel scan)
    k_deg<<<(E + 255) / 256, 256, 0, stream>>>(dstp, deg);
    k_part<<<NBLK, SCAN_B, 0, stream>>>(deg, part, dinv);
    k_scanpart<<<1, SCAN_B, 0, stream>>>(part);
    k_rowfill<<<NBLK, SCAN_B, 0, stream>>>(deg, part, rowstart, fillpos);
    k_fill<<<(E + 255) / 256, 256, 0, stream>>>(srcp, dstp, fillpos, dinv, csr);

    // layer 1
    k_gemm<<<(N + 63) / 64, 256, 0, stream>>>(x, W1, tmp16);
    k_agg<<<(N * 16 + 255) / 256, 256, 0, stream>>>(tmp16, csr, rowstart, dinv, b1, hbuf);
    // layer 2
    k_gemm<<<(N + 63) / 64, 256, 0, stream>>>(hbuf, W2, tmp16);
    k_agg<<<(N * 16 + 255) / 256, 256, 0, stream>>>(tmp16, csr, rowstart, dinv, b2, hbuf);

    // pooling
    int ngrp = (N + 63) / 64;
    k_pool<<<(ngrp * 32 + 255) / 256, 256, 0, stream>>>(hbuf, batch, sums);
    k_cntbs<<<1, G, 0, stream>>>(batch, cnt);

    // fc + heads
    k_fc<<<G, 128, 0, stream>>>(sums, cnt, Wfc, bfc, z);
    k_head<<<(T * G * 2 + 255) / 256, 256, 0, stream>>>(z, Wh, bh, out);
}

// Round 6
// 328.164 us; speedup vs baseline: 1.8899x; 1.0654x over previous
//
#include <hip/hip_runtime.h>
#include <math.h>

constexpr int N = 50000;   // nodes
constexpr int E = 800000;  // edges (without self-loops)
constexpr int F = 128;     // features / hidden
constexpr int G = 256;     // graphs
constexpr int T = 4;       // tasks

constexpr int SCAN_B = 256;
constexpr int NBLK = (N + SCAN_B - 1) / SCAN_B;  // 196
constexpr int XCDS = 8;
constexpr int NPX = (N + XCDS - 1) / XCDS;       // 6250 nodes per XCD slice

typedef __attribute__((ext_vector_type(8))) short short8;
typedef __attribute__((ext_vector_type(4))) float floatx4;

// bf16 <-> fp32 helpers (RNE on pack; values are finite)
__device__ inline float bf2f(unsigned short u) {
    union { unsigned int i; float f; } v;
    v.i = ((unsigned int)u) << 16;
    return v.f;
}
__device__ inline unsigned short f2bf(float f) {
    union { float f; unsigned int i; } v;
    v.f = f;
    unsigned int r = v.i + 0x7FFF + ((v.i >> 16) & 1);
    return (unsigned short)(r >> 16);
}

// ---------------- degree histogram ----------------
__global__ void k_deg(const int* __restrict__ dst, int* __restrict__ deg) {
    int e = blockIdx.x * blockDim.x + threadIdx.x;
    if (e < E) atomicAdd(&deg[dst[e]], 1);
}

// ---------------- two-level scan: block partials + dinv ----------------
__global__ __launch_bounds__(SCAN_B) void k_part(const int* __restrict__ deg,
                                                 int* __restrict__ part,
                                                 float* __restrict__ dinv) {
    __shared__ int s[SCAN_B];
    int t = threadIdx.x;
    int i = blockIdx.x * SCAN_B + t;
    int v = (i < N) ? deg[i] : 0;
    if (i < N) dinv[i] = rsqrtf((float)(v + 1));  // +1 self-loop
    s[t] = v;
    __syncthreads();
#pragma unroll
    for (int off = SCAN_B / 2; off > 0; off >>= 1) {
        if (t < off) s[t] += s[t + off];
        __syncthreads();
    }
    if (t == 0) part[blockIdx.x] = s[0];
}

// ---------------- scan the 196 partials (exclusive) ----------------
__global__ __launch_bounds__(SCAN_B) void k_scanpart(int* __restrict__ part) {
    __shared__ int s[SCAN_B];
    int t = threadIdx.x;
    int v = (t < NBLK) ? part[t] : 0;
    s[t] = v;
    __syncthreads();
    for (int off = 1; off < SCAN_B; off <<= 1) {
        int u = (t >= off) ? s[t - off] : 0;
        __syncthreads();
        s[t] += u;
        __syncthreads();
    }
    if (t < NBLK) part[t] = s[t] - v;  // exclusive prefix of block sums
}

// ---------------- per-block scan + offset -> rowstart/fillpos ----------------
__global__ __launch_bounds__(SCAN_B) void k_rowfill(const int* __restrict__ deg,
                                                    const int* __restrict__ part,
                                                    int* __restrict__ rowstart,
                                                    int* __restrict__ fillpos) {
    __shared__ int s[SCAN_B];
    int t = threadIdx.x;
    int i = blockIdx.x * SCAN_B + t;
    int v = (i < N) ? deg[i] : 0;
    s[t] = v;
    __syncthreads();
    for (int off = 1; off < SCAN_B; off <<= 1) {
        int u = (t >= off) ? s[t - off] : 0;
        __syncthreads();
        s[t] += u;
        __syncthreads();
    }
    int excl = s[t] - v + part[blockIdx.x];
    if (i < N) {
        rowstart[i] = excl;
        fillpos[i] = excl;
    }
    if (blockIdx.x == 0 && t == 0) rowstart[N] = E;  // total degree == E
}

// ---------------- CSR fill, XCD-partitioned by dst range ----------------
// blockIdx % 8 round-robins over XCDs: each XCD writes only its own contiguous
// csr slice, so partial lines stay in that XCD's L2 until filled (kills the
// 53 MB -> ~8 MB write amplification). dst is re-read 8x from LLC (cheap).
__global__ void k_fill(const int* __restrict__ src, const int* __restrict__ dst,
                       int* __restrict__ fillpos, const float* __restrict__ dinv,
                       int2* __restrict__ csr) {
    int xcd = blockIdx.x & 7;
    int chunk = blockIdx.x >> 3;
    int e = chunk * 256 + threadIdx.x;
    if (e >= E) return;
    int d = dst[e];
    if (d < xcd * NPX || d >= (xcd + 1) * NPX) return;
    int s = src[e];
    int pos = atomicAdd(&fillpos[d], 1);
    csr[pos] = make_int2(s, __float_as_int(dinv[s] * dinv[d]));
}

// ---------------- pack W (fp32) into MFMA-B-fragment order, hi/lo bf16 ----------------
// k = s*32 + q*8 + j ; flat u16 idx = ((s*128 + n)*4 + q)*8 + j
__global__ __launch_bounds__(256) void k_wcast(const float* __restrict__ W,
                                               unsigned short* __restrict__ Whi,
                                               unsigned short* __restrict__ Wlo) {
    int i = blockIdx.x * blockDim.x + threadIdx.x;   // i = k*128 + n
    if (i >= F * F) return;
    int k = i >> 7, n = i & 127;
    float w = W[i];
    unsigned short hi = f2bf(w);
    float lo_f = w - bf2f(hi);
    unsigned short lo = f2bf(lo_f);
    int s = k >> 5, q = (k >> 3) & 3, j = k & 7;
    int idx = (((s * 128 + n) * 4 + q) * 8) + j;
    Whi[idx] = hi;
    Wlo[idx] = lo;
}

// ---------------- C16[N,128](bf16) = A[N,128] @ W[128,128] via bf16 MFMA ----------------
// A staged fp32->bf16 in LDS; W pre-packed hi/lo (2 MFMA per tile => weight
// rounding cancels, only A-cast rounding remains).
__global__ __launch_bounds__(256) void k_gemm(const float* __restrict__ A,
                                              const unsigned short* __restrict__ Wph,
                                              const unsigned short* __restrict__ Wpl,
                                              unsigned short* __restrict__ C16) {
    __shared__ __align__(16) unsigned short Albs[64 * 136];  // row-major, pad 136
    int tid = threadIdx.x;
    int row0 = blockIdx.x * 64;

    const float4* A4 = (const float4*)A;
    for (int f = tid; f < 64 * 32; f += 256) {   // 64 rows x 32 float4
        int r = f >> 5, kq = f & 31;
        int row = row0 + r;
        float4 v = make_float4(0.f, 0.f, 0.f, 0.f);
        if (row < N) v = A4[row * 32 + kq];
        ushort4 o;
        o.x = f2bf(v.x); o.y = f2bf(v.y); o.z = f2bf(v.z); o.w = f2bf(v.w);
        *(ushort4*)&Albs[r * 136 + kq * 4] = o;
    }
    __syncthreads();

    int wv = tid >> 6;        // wave 0..3 -> rows wv*16..wv*16+15
    int lane = tid & 63;
    int c16 = lane & 15;      // m within A-frag / n within B-frag / col of C
    int q = lane >> 4;        // 0..3
    int m = wv * 16 + c16;

    floatx4 acc[8];
#pragma unroll
    for (int nt = 0; nt < 8; ++nt) acc[nt] = (floatx4){0.f, 0.f, 0.f, 0.f};

    const short8* WH = (const short8*)Wph;
    const short8* WL = (const short8*)Wpl;
#pragma unroll
    for (int s = 0; s < 4; ++s) {
        short8 a = *(const short8*)&Albs[m * 136 + s * 32 + q * 8];
        int wb = s * 512 + c16 * 4 + q;  // short8 units
#pragma unroll
        for (int nt = 0; nt < 8; ++nt) {
            acc[nt] = __builtin_amdgcn_mfma_f32_16x16x32_bf16(a, WH[wb + nt * 64], acc[nt], 0, 0, 0);
            acc[nt] = __builtin_amdgcn_mfma_f32_16x16x32_bf16(a, WL[wb + nt * 64], acc[nt], 0, 0, 0);
        }
    }

    // C/D layout: col = lane&15, row = (lane>>4)*4 + reg
    int rbase = row0 + wv * 16 + q * 4;
#pragma unroll
    for (int r = 0; r < 4; ++r) {
        int row = rbase + r;
        if (row < N) {
#pragma unroll
            for (int nt = 0; nt < 8; ++nt)
                C16[row * 128 + nt * 16 + c16] = f2bf(acc[nt][r]);
        }
    }
}

// 8 bf16 (uint4) fma into 8 fp32 accumulators
__device__ inline void fma8(const uint4& u, float c, float* acc) {
    union { unsigned int i; float f; } a;
    a.i = u.x << 16;          acc[0] = fmaf(a.f, c, acc[0]);
    a.i = u.x & 0xFFFF0000u;  acc[1] = fmaf(a.f, c, acc[1]);
    a.i = u.y << 16;          acc[2] = fmaf(a.f, c, acc[2]);
    a.i = u.y & 0xFFFF0000u;  acc[3] = fmaf(a.f, c, acc[3]);
    a.i = u.z << 16;          acc[4] = fmaf(a.f, c, acc[4]);
    a.i = u.z & 0xFFFF0000u;  acc[5] = fmaf(a.f, c, acc[5]);
    a.i = u.w << 16;          acc[6] = fmaf(a.f, c, acc[6]);
    a.i = u.w & 0xFFFF0000u;  acc[7] = fmaf(a.f, c, acc[7]);
}

// ---------------- gather aggregation (bf16 msgs, 16 lanes/row, 4x unroll) ----------------
__global__ __launch_bounds__(256) void k_agg(const unsigned short* __restrict__ tmp16,
                                             const int2* __restrict__ csr,
                                             const int* __restrict__ rowstart,
                                             const float* __restrict__ dinv,
                                             const float* __restrict__ bias,
                                             float* __restrict__ out) {
    int node = (blockIdx.x * blockDim.x + threadIdx.x) >> 4;
    int lane = threadIdx.x & 15;           // 16 B per lane -> 256 B row
    if (node >= N) return;
    const uint4* t8 = (const uint4*)tmp16; // 16 uint4 per row
    float di = dinv[node];
    float c0 = di * di;                    // self-loop coefficient
    float acc[8] = {0.f, 0.f, 0.f, 0.f, 0.f, 0.f, 0.f, 0.f};
    fma8(t8[node * 16 + lane], c0, acc);

    int jb = rowstart[node], je = rowstart[node + 1];
    int j = jb;
    for (; j + 4 <= je; j += 4) {
        int2 e0 = csr[j + 0];
        int2 e1 = csr[j + 1];
        int2 e2 = csr[j + 2];
        int2 e3 = csr[j + 3];
        uint4 u0 = t8[e0.x * 16 + lane];   // 4 independent gathers in flight
        uint4 u1 = t8[e1.x * 16 + lane];
        uint4 u2 = t8[e2.x * 16 + lane];
        uint4 u3 = t8[e3.x * 16 + lane];
        fma8(u0, __int_as_float(e0.y), acc);
        fma8(u1, __int_as_float(e1.y), acc);
        fma8(u2, __int_as_float(e2.y), acc);
        fma8(u3, __int_as_float(e3.y), acc);
    }
    for (; j < je; ++j) {
        int2 e = csr[j];
        fma8(t8[e.x * 16 + lane], __int_as_float(e.y), acc);
    }

    const float4* b4 = (const float4*)bias;
    float4 ba = b4[lane * 2], bb = b4[lane * 2 + 1];
    float4 o0, o1;
    o0.x = fmaxf(acc[0] + ba.x, 0.f);
    o0.y = fmaxf(acc[1] + ba.y, 0.f);
    o0.z = fmaxf(acc[2] + ba.z, 0.f);
    o0.w = fmaxf(acc[3] + ba.w, 0.f);
    o1.x = fmaxf(acc[4] + bb.x, 0.f);
    o1.y = fmaxf(acc[5] + bb.y, 0.f);
    o1.z = fmaxf(acc[6] + bb.z, 0.f);
    o1.w = fmaxf(acc[7] + bb.w, 0.f);
    float4* o4 = (float4*)out;
    o4[node * 32 + lane * 2] = o0;
    o4[node * 32 + lane * 2 + 1] = o1;
}

// ---------------- mean-pool accumulate (batch is sorted) ----------------
__global__ void k_pool(const float* __restrict__ h, const int* __restrict__ batch,
                       float* __restrict__ sums) {
    int grp = (blockIdx.x * blockDim.x + threadIdx.x) >> 5;
    int lane = threadIdx.x & 31;
    int base = grp * 64;
    if (base >= N) return;
    int end = (base + 64 < N) ? base + 64 : N;
    float4 acc = make_float4(0.f, 0.f, 0.f, 0.f);
    const float4* h4 = (const float4*)h;
    int curb = batch[base];
    for (int i = base; i < end; ++i) {
        int b = batch[i];
        if (b != curb) {
            float* sp = &sums[curb * F + lane * 4];
            atomicAdd(sp + 0, acc.x); atomicAdd(sp + 1, acc.y);
            atomicAdd(sp + 2, acc.z); atomicAdd(sp + 3, acc.w);
            acc = make_float4(0.f, 0.f, 0.f, 0.f);
            curb = b;
        }
        float4 v = h4[i * 32 + lane];
        acc.x += v.x; acc.y += v.y; acc.z += v.z; acc.w += v.w;
    }
    float* sp = &sums[curb * F + lane * 4];
    atomicAdd(sp + 0, acc.x); atomicAdd(sp + 1, acc.y);
    atomicAdd(sp + 2, acc.z); atomicAdd(sp + 3, acc.w);
}

// ---------------- graph sizes via binary search over sorted batch ----------------
__global__ void k_cntbs(const int* __restrict__ batch, float* __restrict__ cnt) {
    int g = blockIdx.x * blockDim.x + threadIdx.x;
    if (g >= G) return;
    int lo0 = 0, hi0 = N;                 // lower_bound(g)
    while (lo0 < hi0) {
        int mid = (lo0 + hi0) >> 1;
        if (batch[mid] < g) lo0 = mid + 1; else hi0 = mid;
    }
    int lo1 = lo0, hi1 = N;               // lower_bound(g+1)
    while (lo1 < hi1) {
        int mid = (lo1 + hi1) >> 1;
        if (batch[mid] < g + 1) lo1 = mid + 1; else hi1 = mid;
    }
    cnt[g] = (float)(lo1 - lo0);
}

// ---------------- z = relu(pooled @ Wfc + bfc) ----------------
__global__ __launch_bounds__(128) void k_fc(const float* __restrict__ sums,
                                            const float* __restrict__ cnt,
                                            const float* __restrict__ Wfc,
                                            const float* __restrict__ bfc,
                                            float* __restrict__ z) {
    __shared__ float p[128];
    int g = blockIdx.x, t = threadIdx.x;
    float inv = 1.0f / fmaxf(cnt[g], 1.0f);
    p[t] = sums[g * F + t] * inv;
    __syncthreads();
    float acc = bfc[t];
    for (int k = 0; k < F; ++k) acc = fmaf(p[k], Wfc[k * F + t], acc);
    z[g * F + t] = fmaxf(acc, 0.f);
}

// ---------------- out[t,g,c] = z[g,:] . Wh[t,:,c] + bh[t,c] ----------------
__global__ void k_head(const float* __restrict__ z, const float* __restrict__ Wh,
                       const float* __restrict__ bh, float* __restrict__ out) {
    int o = blockIdx.x * blockDim.x + threadIdx.x;
    if (o >= T * G * 2) return;
    int tt = o >> 9;        // / (G*2)
    int rem = o & 511;
    int g = rem >> 1;
    int c = rem & 1;
    float acc = bh[tt * 2 + c];
    const float* zr = &z[g * F];
    const float* wr = &Wh[tt * F * 2 + c];
    for (int h = 0; h < F; ++h) acc = fmaf(zr[h], wr[h * 2], acc);
    out[o] = acc;
}

extern "C" void kernel_launch(void* const* d_in, const int* in_sizes, int n_in,
                              void* d_out, int out_size, void* d_ws, size_t ws_size,
                              hipStream_t stream) {
    const float* x    = (const float*)d_in[0];
    const int*   ei   = (const int*)d_in[1];      // [2,E]: row0=src, row1=dst
    const int*   batch= (const int*)d_in[2];
    const float* W1   = (const float*)d_in[3];
    const float* b1   = (const float*)d_in[4];
    const float* W2   = (const float*)d_in[5];
    const float* b2   = (const float*)d_in[6];
    const float* Wfc  = (const float*)d_in[7];
    const float* bfc  = (const float*)d_in[8];
    const float* Wh   = (const float*)d_in[9];
    const float* bh   = (const float*)d_in[10];
    float* out = (float*)d_out;

    const int* srcp = ei;
    const int* dstp = ei + E;

    char* w = (char*)d_ws;
    auto alloc = [&](size_t bytes) {
        char* p = w;
        w += (bytes + 255) & ~(size_t)255;
        return p;
    };
    unsigned short* tmp16 = (unsigned short*)alloc((size_t)N * F * 2);
    float* hbuf     = (float*)alloc((size_t)N * F * 4);
    int2*  csr      = (int2*) alloc((size_t)E * 8);
    int*   rowstart = (int*)  alloc((size_t)(N + 1) * 4);
    int*   fillpos  = (int*)  alloc((size_t)N * 4);
    int*   deg      = (int*)  alloc((size_t)N * 4);
    float* dinv     = (float*)alloc((size_t)N * 4);
    int*   part     = (int*)  alloc((size_t)NBLK * 4);
    float* sums     = (float*)alloc((size_t)G * F * 4);
    float* cnt      = (float*)alloc((size_t)G * 4);
    float* z        = (float*)alloc((size_t)G * F * 4);
    unsigned short* w1h = (unsigned short*)alloc((size_t)F * F * 2);
    unsigned short* w1l = (unsigned short*)alloc((size_t)F * F * 2);
    unsigned short* w2h = (unsigned short*)alloc((size_t)F * F * 2);
    unsigned short* w2l = (unsigned short*)alloc((size_t)F * F * 2);

    hipMemsetAsync(deg, 0, (size_t)N * 4, stream);
    hipMemsetAsync(sums, 0, (size_t)G * F * 4, stream);

    // weight packs for MFMA GEMM
    k_wcast<<<(F * F + 255) / 256, 256, 0, stream>>>(W1, w1h, w1l);
    k_wcast<<<(F * F + 255) / 256, 256, 0, stream>>>(W2, w2h, w2l);

    // CSR build (two-level parallel scan; fill is XCD-partitioned)
    k_deg<<<(E + 255) / 256, 256, 0, stream>>>(dstp, deg);
    k_part<<<NBLK, SCAN_B, 0, stream>>>(deg, part, dinv);
    k_scanpart<<<1, SCAN_B, 0, stream>>>(part);
    k_rowfill<<<NBLK, SCAN_B, 0, stream>>>(deg, part, rowstart, fillpos);
    k_fill<<<((E + 255) / 256) * XCDS, 256, 0, stream>>>(srcp, dstp, fillpos, dinv, csr);

    // layer 1
    k_gemm<<<(N + 63) / 64, 256, 0, stream>>>(x, w1h, w1l, tmp16);
    k_agg<<<(N * 16 + 255) / 256, 256, 0, stream>>>(tmp16, csr, rowstart, dinv, b1, hbuf);
    // layer 2
    k_gemm<<<(N + 63) / 64, 256, 0, stream>>>(hbuf, w2h, w2l, tmp16);
    k_agg<<<(N * 16 + 255) / 256, 256, 0, stream>>>(tmp16, csr, rowstart, dinv, b2, hbuf);

    // pooling
    int ngrp = (N + 63) / 64;
    k_pool<<<(ngrp * 32 + 255) / 256, 256, 0, stream>>>(hbuf, batch, sums);
    k_cntbs<<<1, G, 0, stream>>>(batch, cnt);

    // fc + heads
    k_fc<<<G, 128, 0, stream>>>(sums, cnt, Wfc, bfc, z);
    k_head<<<(T * G * 2 + 255) / 256, 256, 0, stream>>>(z, Wh, bh, out);
}

// Round 7
// 324.042 us; speedup vs baseline: 1.9140x; 1.0127x over previous
//
#include <hip/hip_runtime.h>
#include <math.h>

constexpr int N = 50000;   // nodes
constexpr int E = 800000;  // edges (without self-loops)
constexpr int F = 128;     // features / hidden
constexpr int G = 256;     // graphs
constexpr int T = 4;       // tasks

constexpr int SCAN_B = 256;
constexpr int NBLK = (N + SCAN_B - 1) / SCAN_B;  // 196
constexpr int XCDS = 8;
constexpr int NPX = (N + XCDS - 1) / XCDS;       // 6250 nodes per XCD slice

// k_pre block-range layout
constexpr int WC_BLKS  = (F * F + 255) / 256;    // 64
constexpr int DEG_BLKS = (E + 255) / 256;        // 3125
constexpr int SUM_BLKS = (G * F + 255) / 256;    // 128
constexpr int PRE_DEG0 = 2 * WC_BLKS + 1;        // 129
constexpr int PRE_SUM0 = PRE_DEG0 + DEG_BLKS;    // 3254
constexpr int PRE_BLKS = PRE_SUM0 + SUM_BLKS;    // 3382

typedef __attribute__((ext_vector_type(8))) short short8;
typedef __attribute__((ext_vector_type(4))) float floatx4;

// bf16 <-> fp32 helpers (RNE on pack; values are finite)
__device__ inline float bf2f(unsigned short u) {
    union { unsigned int i; float f; } v;
    v.i = ((unsigned int)u) << 16;
    return v.f;
}
__device__ inline unsigned short f2bf(float f) {
    union { float f; unsigned int i; } v;
    v.f = f;
    unsigned int r = v.i + 0x7FFF + ((v.i >> 16) & 1);
    return (unsigned short)(r >> 16);
}
__device__ inline unsigned int pack2bf(float a, float b) {
    return (unsigned int)f2bf(a) | ((unsigned int)f2bf(b) << 16);
}

// pack W (fp32) -> MFMA-B-fragment order, hi/lo bf16 split
// k = s*32 + q*8 + j ; flat u16 idx = ((s*128 + n)*4 + q)*8 + j
__device__ inline void wcast_one(const float* __restrict__ W,
                                 unsigned short* __restrict__ Whi,
                                 unsigned short* __restrict__ Wlo, int i) {
    if (i >= F * F) return;
    int k = i >> 7, n = i & 127;
    float w = W[i];
    unsigned short hi = f2bf(w);
    unsigned short lo = f2bf(w - bf2f(hi));
    int s = k >> 5, q = (k >> 3) & 3, j = k & 7;
    int idx = (((s * 128 + n) * 4 + q) * 8) + j;
    Whi[idx] = hi;
    Wlo[idx] = lo;
}

// ---------------- fused preamble: wcast(W1), wcast(W2), cntbs, deg, zero(sums) ----------------
__global__ __launch_bounds__(256) void k_pre(const float* __restrict__ W1, const float* __restrict__ W2,
                                             unsigned short* __restrict__ w1h, unsigned short* __restrict__ w1l,
                                             unsigned short* __restrict__ w2h, unsigned short* __restrict__ w2l,
                                             const int* __restrict__ dst, int* __restrict__ deg,
                                             const int* __restrict__ batch, float* __restrict__ cnt,
                                             float* __restrict__ sums) {
    int b = blockIdx.x, t = threadIdx.x;
    if (b < WC_BLKS) {
        wcast_one(W1, w1h, w1l, b * 256 + t);
    } else if (b < 2 * WC_BLKS) {
        wcast_one(W2, w2h, w2l, (b - WC_BLKS) * 256 + t);
    } else if (b == 2 * WC_BLKS) {
        // graph sizes via binary search over sorted batch (t == g)
        int g = t;
        int lo0 = 0, hi0 = N;
        while (lo0 < hi0) { int m = (lo0 + hi0) >> 1; if (batch[m] < g) lo0 = m + 1; else hi0 = m; }
        int lo1 = lo0, hi1 = N;
        while (lo1 < hi1) { int m = (lo1 + hi1) >> 1; if (batch[m] < g + 1) lo1 = m + 1; else hi1 = m; }
        cnt[g] = (float)(lo1 - lo0);
    } else if (b < PRE_SUM0) {
        int e = (b - PRE_DEG0) * 256 + t;
        if (e < E) atomicAdd(&deg[dst[e]], 1);
    } else {
        int i = (b - PRE_SUM0) * 256 + t;
        if (i < G * F) sums[i] = 0.f;
    }
}

// ---------------- two-level scan: block partials + dinv ----------------
__global__ __launch_bounds__(SCAN_B) void k_part(const int* __restrict__ deg,
                                                 int* __restrict__ part,
                                                 float* __restrict__ dinv) {
    __shared__ int s[SCAN_B];
    int t = threadIdx.x;
    int i = blockIdx.x * SCAN_B + t;
    int v = (i < N) ? deg[i] : 0;
    if (i < N) dinv[i] = rsqrtf((float)(v + 1));  // +1 self-loop
    s[t] = v;
    __syncthreads();
#pragma unroll
    for (int off = SCAN_B / 2; off > 0; off >>= 1) {
        if (t < off) s[t] += s[t + off];
        __syncthreads();
    }
    if (t == 0) part[blockIdx.x] = s[0];
}

// ---------------- scan the 196 partials (exclusive) ----------------
__global__ __launch_bounds__(SCAN_B) void k_scanpart(int* __restrict__ part) {
    __shared__ int s[SCAN_B];
    int t = threadIdx.x;
    int v = (t < NBLK) ? part[t] : 0;
    s[t] = v;
    __syncthreads();
    for (int off = 1; off < SCAN_B; off <<= 1) {
        int u = (t >= off) ? s[t - off] : 0;
        __syncthreads();
        s[t] += u;
        __syncthreads();
    }
    if (t < NBLK) part[t] = s[t] - v;  // exclusive prefix of block sums
}

// ---------------- per-block scan + offset -> rowstart/fillpos ----------------
__global__ __launch_bounds__(SCAN_B) void k_rowfill(const int* __restrict__ deg,
                                                    const int* __restrict__ part,
                                                    int* __restrict__ rowstart,
                                                    int* __restrict__ fillpos) {
    __shared__ int s[SCAN_B];
    int t = threadIdx.x;
    int i = blockIdx.x * SCAN_B + t;
    int v = (i < N) ? deg[i] : 0;
    s[t] = v;
    __syncthreads();
    for (int off = 1; off < SCAN_B; off <<= 1) {
        int u = (t >= off) ? s[t - off] : 0;
        __syncthreads();
        s[t] += u;
        __syncthreads();
    }
    int excl = s[t] - v + part[blockIdx.x];
    if (i < N) {
        rowstart[i] = excl;
        fillpos[i] = excl;
    }
    if (blockIdx.x == 0 && t == 0) rowstart[N] = E;  // total degree == E
}

// ---------------- CSR fill, XCD-partitioned by dst range ----------------
__global__ void k_fill(const int* __restrict__ src, const int* __restrict__ dst,
                       int* __restrict__ fillpos, const float* __restrict__ dinv,
                       int2* __restrict__ csr) {
    int xcd = blockIdx.x & 7;
    int chunk = blockIdx.x >> 3;
    int e = chunk * 256 + threadIdx.x;
    if (e >= E) return;
    int d = dst[e];
    if (d < xcd * NPX || d >= (xcd + 1) * NPX) return;
    int s = src[e];
    int pos = atomicAdd(&fillpos[d], 1);
    csr[pos] = make_int2(s, __float_as_int(dinv[s] * dinv[d]));
}

// ---------------- C16[N,128](bf16) = A[N,128] @ W[128,128] via bf16 MFMA ----------------
// W pre-packed hi/lo (2 MFMA per tile => only A-cast rounding remains).
template <bool ABF16>
__global__ __launch_bounds__(256) void k_gemm(const void* __restrict__ Ain,
                                              const unsigned short* __restrict__ Wph,
                                              const unsigned short* __restrict__ Wpl,
                                              unsigned short* __restrict__ C16) {
    __shared__ __align__(16) unsigned short Albs[64 * 136];  // row-major, pad 136
    int tid = threadIdx.x;
    int row0 = blockIdx.x * 64;

    if (ABF16) {
        const uint4* A8 = (const uint4*)Ain;              // 16 uint4 per row
        for (int f = tid; f < 64 * 16; f += 256) {
            int r = f >> 4, kq = f & 15;
            int row = row0 + r;
            uint4 v = make_uint4(0u, 0u, 0u, 0u);
            if (row < N) v = A8[row * 16 + kq];
            *(uint4*)&Albs[r * 136 + kq * 8] = v;
        }
    } else {
        const float4* A4 = (const float4*)Ain;
        for (int f = tid; f < 64 * 32; f += 256) {
            int r = f >> 5, kq = f & 31;
            int row = row0 + r;
            float4 v = make_float4(0.f, 0.f, 0.f, 0.f);
            if (row < N) v = A4[row * 32 + kq];
            ushort4 o;
            o.x = f2bf(v.x); o.y = f2bf(v.y); o.z = f2bf(v.z); o.w = f2bf(v.w);
            *(ushort4*)&Albs[r * 136 + kq * 4] = o;
        }
    }
    __syncthreads();

    int wv = tid >> 6;        // wave 0..3 -> rows wv*16..wv*16+15
    int lane = tid & 63;
    int c16 = lane & 15;
    int q = lane >> 4;        // 0..3
    int m = wv * 16 + c16;

    floatx4 acc[8];
#pragma unroll
    for (int nt = 0; nt < 8; ++nt) acc[nt] = (floatx4){0.f, 0.f, 0.f, 0.f};

    const short8* WH = (const short8*)Wph;
    const short8* WL = (const short8*)Wpl;
#pragma unroll
    for (int s = 0; s < 4; ++s) {
        short8 a = *(const short8*)&Albs[m * 136 + s * 32 + q * 8];
        int wb = s * 512 + c16 * 4 + q;  // short8 units
#pragma unroll
        for (int nt = 0; nt < 8; ++nt) {
            acc[nt] = __builtin_amdgcn_mfma_f32_16x16x32_bf16(a, WH[wb + nt * 64], acc[nt], 0, 0, 0);
            acc[nt] = __builtin_amdgcn_mfma_f32_16x16x32_bf16(a, WL[wb + nt * 64], acc[nt], 0, 0, 0);
        }
    }

    // C/D layout: col = lane&15, row = (lane>>4)*4 + reg
    int rbase = row0 + wv * 16 + q * 4;
#pragma unroll
    for (int r = 0; r < 4; ++r) {
        int row = rbase + r;
        if (row < N) {
#pragma unroll
            for (int nt = 0; nt < 8; ++nt)
                C16[row * 128 + nt * 16 + c16] = f2bf(acc[nt][r]);
        }
    }
}

// 8 bf16 (uint4) fma into 8 fp32 accumulators
__device__ inline void fma8(const uint4& u, float c, float* acc) {
    union { unsigned int i; float f; } a;
    a.i = u.x << 16;          acc[0] = fmaf(a.f, c, acc[0]);
    a.i = u.x & 0xFFFF0000u;  acc[1] = fmaf(a.f, c, acc[1]);
    a.i = u.y << 16;          acc[2] = fmaf(a.f, c, acc[2]);
    a.i = u.y & 0xFFFF0000u;  acc[3] = fmaf(a.f, c, acc[3]);
    a.i = u.z << 16;          acc[4] = fmaf(a.f, c, acc[4]);
    a.i = u.z & 0xFFFF0000u;  acc[5] = fmaf(a.f, c, acc[5]);
    a.i = u.w << 16;          acc[6] = fmaf(a.f, c, acc[6]);
    a.i = u.w & 0xFFFF0000u;  acc[7] = fmaf(a.f, c, acc[7]);
}

// ---------------- gather aggregation (bf16 msgs, 16 lanes/row, 8x in flight) ----------------
// tail handled by clamped duplicate-src + zero coef (no serial remainder)
__global__ __launch_bounds__(256) void k_agg(const unsigned short* __restrict__ tmp16,
                                             const int2* __restrict__ csr,
                                             const int* __restrict__ rowstart,
                                             const float* __restrict__ dinv,
                                             const float* __restrict__ bias,
                                             unsigned short* __restrict__ out16) {
    int node = (blockIdx.x * blockDim.x + threadIdx.x) >> 4;
    int lane = threadIdx.x & 15;           // 16 B per lane -> 256 B row
    if (node >= N) return;
    const uint4* t8 = (const uint4*)tmp16; // 16 uint4 per row
    float di = dinv[node];
    float c0 = di * di;                    // self-loop coefficient
    float acc[8] = {0.f, 0.f, 0.f, 0.f, 0.f, 0.f, 0.f, 0.f};
    fma8(t8[node * 16 + lane], c0, acc);

    int jb = rowstart[node], je = rowstart[node + 1];
    for (int j = jb; j < je; j += 8) {
        int2 e[8];
#pragma unroll
        for (int k = 0; k < 8; ++k) {
            int idx = j + k;
            int2 t = csr[idx < je ? idx : je - 1];
            if (idx >= je) t.y = 0;        // zero coef; duplicate src hits cache
            e[k] = t;
        }
        uint4 u[8];
#pragma unroll
        for (int k = 0; k < 8; ++k) u[k] = t8[e[k].x * 16 + lane];
#pragma unroll
        for (int k = 0; k < 8; ++k) fma8(u[k], __int_as_float(e[k].y), acc);
    }

    const float4* b4 = (const float4*)bias;
    float4 ba = b4[lane * 2], bb = b4[lane * 2 + 1];
    uint4 o;
    o.x = pack2bf(fmaxf(acc[0] + ba.x, 0.f), fmaxf(acc[1] + ba.y, 0.f));
    o.y = pack2bf(fmaxf(acc[2] + ba.z, 0.f), fmaxf(acc[3] + ba.w, 0.f));
    o.z = pack2bf(fmaxf(acc[4] + bb.x, 0.f), fmaxf(acc[5] + bb.y, 0.f));
    o.w = pack2bf(fmaxf(acc[6] + bb.z, 0.f), fmaxf(acc[7] + bb.w, 0.f));
    ((uint4*)out16)[node * 16 + lane] = o;
}

// ---------------- mean-pool accumulate over bf16 h (batch is sorted) ----------------
__global__ void k_pool(const unsigned short* __restrict__ h16, const int* __restrict__ batch,
                       float* __restrict__ sums) {
    int grp = (blockIdx.x * blockDim.x + threadIdx.x) >> 4;
    int lane = threadIdx.x & 15;
    int base = grp * 64;
    if (base >= N) return;
    int end = (base + 64 < N) ? base + 64 : N;
    float acc[8] = {0.f, 0.f, 0.f, 0.f, 0.f, 0.f, 0.f, 0.f};
    const uint4* h4 = (const uint4*)h16;
    int curb = batch[base];
    for (int i = base; i < end; ++i) {
        int b = batch[i];
        if (b != curb) {
            float* sp = &sums[curb * F + lane * 8];
#pragma unroll
            for (int k = 0; k < 8; ++k) { atomicAdd(sp + k, acc[k]); acc[k] = 0.f; }
            curb = b;
        }
        fma8(h4[i * 16 + lane], 1.0f, acc);
    }
    float* sp = &sums[curb * F + lane * 8];
#pragma unroll
    for (int k = 0; k < 8; ++k) atomicAdd(sp + k, acc[k]);
}

// ---------------- z = relu(pooled @ Wfc + bfc) ----------------
__global__ __launch_bounds__(128) void k_fc(const float* __restrict__ sums,
                                            const float* __restrict__ cnt,
                                            const float* __restrict__ Wfc,
                                            const float* __restrict__ bfc,
                                            float* __restrict__ z) {
    __shared__ float p[128];
    int g = blockIdx.x, t = threadIdx.x;
    float inv = 1.0f / fmaxf(cnt[g], 1.0f);
    p[t] = sums[g * F + t] * inv;
    __syncthreads();
    float acc = bfc[t];
    for (int k = 0; k < F; ++k) acc = fmaf(p[k], Wfc[k * F + t], acc);
    z[g * F + t] = fmaxf(acc, 0.f);
}

// ---------------- out[t,g,c] = z[g,:] . Wh[t,:,c] + bh[t,c] ----------------
__global__ void k_head(const float* __restrict__ z, const float* __restrict__ Wh,
                       const float* __restrict__ bh, float* __restrict__ out) {
    int o = blockIdx.x * blockDim.x + threadIdx.x;
    if (o >= T * G * 2) return;
    int tt = o >> 9;        // / (G*2)
    int rem = o & 511;
    int g = rem >> 1;
    int c = rem & 1;
    float acc = bh[tt * 2 + c];
    const float* zr = &z[g * F];
    const float* wr = &Wh[tt * F * 2 + c];
    for (int h = 0; h < F; ++h) acc = fmaf(zr[h], wr[h * 2], acc);
    out[o] = acc;
}

extern "C" void kernel_launch(void* const* d_in, const int* in_sizes, int n_in,
                              void* d_out, int out_size, void* d_ws, size_t ws_size,
                              hipStream_t stream) {
    const float* x    = (const float*)d_in[0];
    const int*   ei   = (const int*)d_in[1];      // [2,E]: row0=src, row1=dst
    const int*   batch= (const int*)d_in[2];
    const float* W1   = (const float*)d_in[3];
    const float* b1   = (const float*)d_in[4];
    const float* W2   = (const float*)d_in[5];
    const float* b2   = (const float*)d_in[6];
    const float* Wfc  = (const float*)d_in[7];
    const float* bfc  = (const float*)d_in[8];
    const float* Wh   = (const float*)d_in[9];
    const float* bh   = (const float*)d_in[10];
    float* out = (float*)d_out;

    const int* srcp = ei;
    const int* dstp = ei + E;

    char* w = (char*)d_ws;
    auto alloc = [&](size_t bytes) {
        char* p = w;
        w += (bytes + 255) & ~(size_t)255;
        return p;
    };
    unsigned short* tmp16 = (unsigned short*)alloc((size_t)N * F * 2);
    unsigned short* hbuf16= (unsigned short*)alloc((size_t)N * F * 2);
    int2*  csr      = (int2*) alloc((size_t)E * 8);
    int*   rowstart = (int*)  alloc((size_t)(N + 1) * 4);
    int*   fillpos  = (int*)  alloc((size_t)N * 4);
    int*   deg      = (int*)  alloc((size_t)N * 4);
    float* dinv     = (float*)alloc((size_t)N * 4);
    int*   part     = (int*)  alloc((size_t)NBLK * 4);
    float* sums     = (float*)alloc((size_t)G * F * 4);
    float* cnt      = (float*)alloc((size_t)G * 4);
    float* z        = (float*)alloc((size_t)G * F * 4);
    unsigned short* w1h = (unsigned short*)alloc((size_t)F * F * 2);
    unsigned short* w1l = (unsigned short*)alloc((size_t)F * F * 2);
    unsigned short* w2h = (unsigned short*)alloc((size_t)F * F * 2);
    unsigned short* w2l = (unsigned short*)alloc((size_t)F * F * 2);

    hipMemsetAsync(deg, 0, (size_t)N * 4, stream);

    // fused preamble: wcast W1/W2, cntbs, deg histogram, zero sums
    k_pre<<<PRE_BLKS, 256, 0, stream>>>(W1, W2, w1h, w1l, w2h, w2l,
                                        dstp, deg, batch, cnt, sums);

    // CSR build (two-level parallel scan; fill is XCD-partitioned)
    k_part<<<NBLK, SCAN_B, 0, stream>>>(deg, part, dinv);
    k_scanpart<<<1, SCAN_B, 0, stream>>>(part);
    k_rowfill<<<NBLK, SCAN_B, 0, stream>>>(deg, part, rowstart, fillpos);
    k_fill<<<((E + 255) / 256) * XCDS, 256, 0, stream>>>(srcp, dstp, fillpos, dinv, csr);

    // layer 1
    k_gemm<false><<<(N + 63) / 64, 256, 0, stream>>>(x, w1h, w1l, tmp16);
    k_agg<<<(N * 16 + 255) / 256, 256, 0, stream>>>(tmp16, csr, rowstart, dinv, b1, hbuf16);
    // layer 2
    k_gemm<true><<<(N + 63) / 64, 256, 0, stream>>>(hbuf16, w2h, w2l, tmp16);
    k_agg<<<(N * 16 + 255) / 256, 256, 0, stream>>>(tmp16, csr, rowstart, dinv, b2, hbuf16);

    // pooling
    int ngrp = (N + 63) / 64;
    k_pool<<<(ngrp * 16 + 255) / 256, 256, 0, stream>>>(hbuf16, batch, sums);

    // fc + heads
    k_fc<<<G, 128, 0, stream>>>(sums, cnt, Wfc, bfc, z);
    k_head<<<(T * G * 2 + 255) / 256, 256, 0, stream>>>(z, Wh, bh, out);
}

// Round 8
// 310.331 us; speedup vs baseline: 1.9985x; 1.0442x over previous
//
#include <hip/hip_runtime.h>
#include <math.h>

constexpr int N = 50000;   // nodes
constexpr int E = 800000;  // edges (without self-loops)
constexpr int F = 128;     // features / hidden
constexpr int G = 256;     // graphs
constexpr int T = 4;       // tasks

constexpr int SCAN_B = 256;
constexpr int NBLK = (N + SCAN_B - 1) / SCAN_B;  // 196
constexpr int XCDS = 8;
constexpr int NPX = (N + XCDS - 1) / XCDS;       // 6250 nodes per XCD slice

// k_pre block-range layout
constexpr int WC_BLKS  = (F * F + 255) / 256;    // 64
constexpr int DEG_BLKS = (E + 255) / 256;        // 3125
constexpr int SUM_BLKS = (G * F + 255) / 256;    // 128
constexpr int PRE_DEG0 = 2 * WC_BLKS + 1;        // 129
constexpr int PRE_SUM0 = PRE_DEG0 + DEG_BLKS;    // 3254
constexpr int PRE_BLKS = PRE_SUM0 + SUM_BLKS;    // 3382

// fused fill+gemm1 layout
constexpr int GB1 = (N + 63) / 64;               // 782 gemm blocks
constexpr int FILL_BLKS = DEG_BLKS * XCDS;       // 25000

typedef __attribute__((ext_vector_type(8))) short short8;
typedef __attribute__((ext_vector_type(4))) float floatx4;

// bf16 <-> fp32 helpers (RNE on pack; values are finite)
__device__ inline float bf2f(unsigned short u) {
    union { unsigned int i; float f; } v;
    v.i = ((unsigned int)u) << 16;
    return v.f;
}
__device__ inline unsigned short f2bf(float f) {
    union { float f; unsigned int i; } v;
    v.f = f;
    unsigned int r = v.i + 0x7FFF + ((v.i >> 16) & 1);
    return (unsigned short)(r >> 16);
}
__device__ inline unsigned int pack2bf(float a, float b) {
    return (unsigned int)f2bf(a) | ((unsigned int)f2bf(b) << 16);
}

// pack W (fp32) -> MFMA-B-fragment order, hi/lo bf16 split
// k = s*32 + q*8 + j ; flat u16 idx = ((s*128 + n)*4 + q)*8 + j
__device__ inline void wcast_one(const float* __restrict__ W,
                                 unsigned short* __restrict__ Whi,
                                 unsigned short* __restrict__ Wlo, int i) {
    if (i >= F * F) return;
    int k = i >> 7, n = i & 127;
    float w = W[i];
    unsigned short hi = f2bf(w);
    unsigned short lo = f2bf(w - bf2f(hi));
    int s = k >> 5, q = (k >> 3) & 3, j = k & 7;
    int idx = (((s * 128 + n) * 4 + q) * 8) + j;
    Whi[idx] = hi;
    Wlo[idx] = lo;
}

// ---------------- fused preamble: wcast(W1), wcast(W2), cntbs, deg8 hist, zero(sums) ----------------
// deg is 8-way privatized (deg8[c][N], c = blockIdx&7): same atomic count but
// 8x the distinct lines -> 8x memory-side atomic line-queue parallelism.
__global__ __launch_bounds__(256) void k_pre(const float* __restrict__ W1, const float* __restrict__ W2,
                                             unsigned short* __restrict__ w1h, unsigned short* __restrict__ w1l,
                                             unsigned short* __restrict__ w2h, unsigned short* __restrict__ w2l,
                                             const int* __restrict__ dst, int* __restrict__ deg8,
                                             const int* __restrict__ batch, float* __restrict__ cnt,
                                             float* __restrict__ sums) {
    int b = blockIdx.x, t = threadIdx.x;
    if (b < WC_BLKS) {
        wcast_one(W1, w1h, w1l, b * 256 + t);
    } else if (b < 2 * WC_BLKS) {
        wcast_one(W2, w2h, w2l, (b - WC_BLKS) * 256 + t);
    } else if (b == 2 * WC_BLKS) {
        // graph sizes via binary search over sorted batch (t == g)
        int g = t;
        int lo0 = 0, hi0 = N;
        while (lo0 < hi0) { int m = (lo0 + hi0) >> 1; if (batch[m] < g) lo0 = m + 1; else hi0 = m; }
        int lo1 = lo0, hi1 = N;
        while (lo1 < hi1) { int m = (lo1 + hi1) >> 1; if (batch[m] < g + 1) lo1 = m + 1; else hi1 = m; }
        cnt[g] = (float)(lo1 - lo0);
    } else if (b < PRE_SUM0) {
        int e = (b - PRE_DEG0) * 256 + t;
        if (e < E) atomicAdd(&deg8[(b & 7) * N + dst[e]], 1);
    } else {
        int i = (b - PRE_SUM0) * 256 + t;
        if (i < G * F) sums[i] = 0.f;
    }
}

// ---------------- two-level scan: sum deg8 copies, block partials + dinv ----------------
__global__ __launch_bounds__(SCAN_B) void k_part(const int* __restrict__ deg8,
                                                 int* __restrict__ deg,
                                                 int* __restrict__ part,
                                                 float* __restrict__ dinv) {
    __shared__ int s[SCAN_B];
    int t = threadIdx.x;
    int i = blockIdx.x * SCAN_B + t;
    int v = 0;
    if (i < N) {
#pragma unroll
        for (int c = 0; c < 8; ++c) v += deg8[c * N + i];
        deg[i] = v;
        dinv[i] = rsqrtf((float)(v + 1));  // +1 self-loop
    }
    s[t] = v;
    __syncthreads();
#pragma unroll
    for (int off = SCAN_B / 2; off > 0; off >>= 1) {
        if (t < off) s[t] += s[t + off];
        __syncthreads();
    }
    if (t == 0) part[blockIdx.x] = s[0];
}

// ---------------- scan the 196 partials (exclusive) ----------------
__global__ __launch_bounds__(SCAN_B) void k_scanpart(int* __restrict__ part) {
    __shared__ int s[SCAN_B];
    int t = threadIdx.x;
    int v = (t < NBLK) ? part[t] : 0;
    s[t] = v;
    __syncthreads();
    for (int off = 1; off < SCAN_B; off <<= 1) {
        int u = (t >= off) ? s[t - off] : 0;
        __syncthreads();
        s[t] += u;
        __syncthreads();
    }
    if (t < NBLK) part[t] = s[t] - v;  // exclusive prefix of block sums
}

// ---------------- per-block scan + offset -> rowstart/fillpos ----------------
__global__ __launch_bounds__(SCAN_B) void k_rowfill(const int* __restrict__ deg,
                                                    const int* __restrict__ part,
                                                    int* __restrict__ rowstart,
                                                    int* __restrict__ fillpos) {
    __shared__ int s[SCAN_B];
    int t = threadIdx.x;
    int i = blockIdx.x * SCAN_B + t;
    int v = (i < N) ? deg[i] : 0;
    s[t] = v;
    __syncthreads();
    for (int off = 1; off < SCAN_B; off <<= 1) {
        int u = (t >= off) ? s[t - off] : 0;
        __syncthreads();
        s[t] += u;
        __syncthreads();
    }
    int excl = s[t] - v + part[blockIdx.x];
    if (i < N) {
        rowstart[i] = excl;
        fillpos[i] = excl;
    }
    if (blockIdx.x == 0 && t == 0) rowstart[N] = E;  // total degree == E
}

// ---------------- MFMA GEMM body: C16[64,128](bf16) = A-tile @ W ----------------
// W pre-packed hi/lo (2 MFMA per tile => only A-cast rounding remains).
template <bool ABF16>
__device__ __forceinline__ void gemm_body(const void* __restrict__ Ain,
                                          const unsigned short* __restrict__ Wph,
                                          const unsigned short* __restrict__ Wpl,
                                          unsigned short* __restrict__ C16,
                                          int row0, int tid) {
    __shared__ __align__(16) unsigned short Albs[64 * 136];  // row-major, pad 136

    if (ABF16) {
        const uint4* A8 = (const uint4*)Ain;              // 16 uint4 per row
        for (int f = tid; f < 64 * 16; f += 256) {
            int r = f >> 4, kq = f & 15;
            int row = row0 + r;
            uint4 v = make_uint4(0u, 0u, 0u, 0u);
            if (row < N) v = A8[row * 16 + kq];
            *(uint4*)&Albs[r * 136 + kq * 8] = v;
        }
    } else {
        const float4* A4 = (const float4*)Ain;
        for (int f = tid; f < 64 * 32; f += 256) {
            int r = f >> 5, kq = f & 31;
            int row = row0 + r;
            float4 v = make_float4(0.f, 0.f, 0.f, 0.f);
            if (row < N) v = A4[row * 32 + kq];
            ushort4 o;
            o.x = f2bf(v.x); o.y = f2bf(v.y); o.z = f2bf(v.z); o.w = f2bf(v.w);
            *(ushort4*)&Albs[r * 136 + kq * 4] = o;
        }
    }
    __syncthreads();

    int wv = tid >> 6;        // wave 0..3 -> rows wv*16..wv*16+15
    int lane = tid & 63;
    int c16 = lane & 15;
    int q = lane >> 4;        // 0..3
    int m = wv * 16 + c16;

    floatx4 acc[8];
#pragma unroll
    for (int nt = 0; nt < 8; ++nt) acc[nt] = (floatx4){0.f, 0.f, 0.f, 0.f};

    const short8* WH = (const short8*)Wph;
    const short8* WL = (const short8*)Wpl;
#pragma unroll
    for (int s = 0; s < 4; ++s) {
        short8 a = *(const short8*)&Albs[m * 136 + s * 32 + q * 8];
        int wb = s * 512 + c16 * 4 + q;  // short8 units
#pragma unroll
        for (int nt = 0; nt < 8; ++nt) {
            acc[nt] = __builtin_amdgcn_mfma_f32_16x16x32_bf16(a, WH[wb + nt * 64], acc[nt], 0, 0, 0);
            acc[nt] = __builtin_amdgcn_mfma_f32_16x16x32_bf16(a, WL[wb + nt * 64], acc[nt], 0, 0, 0);
        }
    }

    // C/D layout: col = lane&15, row = (lane>>4)*4 + reg
    int rbase = row0 + wv * 16 + q * 4;
#pragma unroll
    for (int r = 0; r < 4; ++r) {
        int row = rbase + r;
        if (row < N) {
#pragma unroll
            for (int nt = 0; nt < 8; ++nt)
                C16[row * 128 + nt * 16 + c16] = f2bf(acc[nt][r]);
        }
    }
}

template <bool ABF16>
__global__ __launch_bounds__(256) void k_gemm(const void* __restrict__ Ain,
                                              const unsigned short* __restrict__ Wph,
                                              const unsigned short* __restrict__ Wpl,
                                              unsigned short* __restrict__ C16) {
    gemm_body<ABF16>(Ain, Wph, Wpl, C16, blockIdx.x * 64, threadIdx.x);
}

// ---------------- fused: gemm1 (blocks 0..GB1) + XCD-partitioned CSR fill ----------------
// Both depend only on {k_pre, k_rowfill} outputs; latency-bound fill waves and
// MFMA waves co-schedule on the same CUs.
__global__ __launch_bounds__(256) void k_fillgemm(const float* __restrict__ x,
                                                  const unsigned short* __restrict__ w1h,
                                                  const unsigned short* __restrict__ w1l,
                                                  unsigned short* __restrict__ tmp16,
                                                  const int* __restrict__ src,
                                                  const int* __restrict__ dst,
                                                  int* __restrict__ fillpos,
                                                  const float* __restrict__ dinv,
                                                  int2* __restrict__ csr) {
    int b = blockIdx.x;
    if (b < GB1) {
        gemm_body<false>(x, w1h, w1l, tmp16, b * 64, threadIdx.x);
        return;
    }
    int b2 = b - GB1;
    int xcd = b2 & 7;
    int chunk = b2 >> 3;
    int e = chunk * 256 + threadIdx.x;
    if (e >= E) return;
    int d = dst[e];
    if (d < xcd * NPX || d >= (xcd + 1) * NPX) return;
    int s = src[e];
    int pos = atomicAdd(&fillpos[d], 1);
    csr[pos] = make_int2(s, __float_as_int(dinv[s] * dinv[d]));
}

// 8 bf16 (uint4) fma into 8 fp32 accumulators
__device__ inline void fma8(const uint4& u, float c, float* acc) {
    union { unsigned int i; float f; } a;
    a.i = u.x << 16;          acc[0] = fmaf(a.f, c, acc[0]);
    a.i = u.x & 0xFFFF0000u;  acc[1] = fmaf(a.f, c, acc[1]);
    a.i = u.y << 16;          acc[2] = fmaf(a.f, c, acc[2]);
    a.i = u.y & 0xFFFF0000u;  acc[3] = fmaf(a.f, c, acc[3]);
    a.i = u.z << 16;          acc[4] = fmaf(a.f, c, acc[4]);
    a.i = u.z & 0xFFFF0000u;  acc[5] = fmaf(a.f, c, acc[5]);
    a.i = u.w << 16;          acc[6] = fmaf(a.f, c, acc[6]);
    a.i = u.w & 0xFFFF0000u;  acc[7] = fmaf(a.f, c, acc[7]);
}

// ---------------- gather aggregation (bf16 msgs, 16 lanes/row, 8x in flight) ----------------
__global__ __launch_bounds__(256) void k_agg(const unsigned short* __restrict__ tmp16,
                                             const int2* __restrict__ csr,
                                             const int* __restrict__ rowstart,
                                             const float* __restrict__ dinv,
                                             const float* __restrict__ bias,
                                             unsigned short* __restrict__ out16) {
    int node = (blockIdx.x * blockDim.x + threadIdx.x) >> 4;
    int lane = threadIdx.x & 15;           // 16 B per lane -> 256 B row
    if (node >= N) return;
    const uint4* t8 = (const uint4*)tmp16; // 16 uint4 per row
    float di = dinv[node];
    float c0 = di * di;                    // self-loop coefficient
    float acc[8] = {0.f, 0.f, 0.f, 0.f, 0.f, 0.f, 0.f, 0.f};
    fma8(t8[node * 16 + lane], c0, acc);

    int jb = rowstart[node], je = rowstart[node + 1];
    for (int j = jb; j < je; j += 8) {
        int2 e[8];
#pragma unroll
        for (int k = 0; k < 8; ++k) {
            int idx = j + k;
            int2 t = csr[idx < je ? idx : je - 1];
            if (idx >= je) t.y = 0;        // zero coef; duplicate src hits cache
            e[k] = t;
        }
        uint4 u[8];
#pragma unroll
        for (int k = 0; k < 8; ++k) u[k] = t8[e[k].x * 16 + lane];
#pragma unroll
        for (int k = 0; k < 8; ++k) fma8(u[k], __int_as_float(e[k].y), acc);
    }

    const float4* b4 = (const float4*)bias;
    float4 ba = b4[lane * 2], bb = b4[lane * 2 + 1];
    uint4 o;
    o.x = pack2bf(fmaxf(acc[0] + ba.x, 0.f), fmaxf(acc[1] + ba.y, 0.f));
    o.y = pack2bf(fmaxf(acc[2] + ba.z, 0.f), fmaxf(acc[3] + ba.w, 0.f));
    o.z = pack2bf(fmaxf(acc[4] + bb.x, 0.f), fmaxf(acc[5] + bb.y, 0.f));
    o.w = pack2bf(fmaxf(acc[6] + bb.z, 0.f), fmaxf(acc[7] + bb.w, 0.f));
    ((uint4*)out16)[node * 16 + lane] = o;
}

// ---------------- mean-pool accumulate over bf16 h (batch is sorted) ----------------
__global__ void k_pool(const unsigned short* __restrict__ h16, const int* __restrict__ batch,
                       float* __restrict__ sums) {
    int grp = (blockIdx.x * blockDim.x + threadIdx.x) >> 4;
    int lane = threadIdx.x & 15;
    int base = grp * 64;
    if (base >= N) return;
    int end = (base + 64 < N) ? base + 64 : N;
    float acc[8] = {0.f, 0.f, 0.f, 0.f, 0.f, 0.f, 0.f, 0.f};
    const uint4* h4 = (const uint4*)h16;
    int curb = batch[base];
    for (int i = base; i < end; ++i) {
        int b = batch[i];
        if (b != curb) {
            float* sp = &sums[curb * F + lane * 8];
#pragma unroll
            for (int k = 0; k < 8; ++k) { atomicAdd(sp + k, acc[k]); acc[k] = 0.f; }
            curb = b;
        }
        fma8(h4[i * 16 + lane], 1.0f, acc);
    }
    float* sp = &sums[curb * F + lane * 8];
#pragma unroll
    for (int k = 0; k < 8; ++k) atomicAdd(sp + k, acc[k]);
}

// ---------------- z = relu(pooled @ Wfc + bfc) ----------------
__global__ __launch_bounds__(128) void k_fc(const float* __restrict__ sums,
                                            const float* __restrict__ cnt,
                                            const float* __restrict__ Wfc,
                                            const float* __restrict__ bfc,
                                            float* __restrict__ z) {
    __shared__ float p[128];
    int g = blockIdx.x, t = threadIdx.x;
    float inv = 1.0f / fmaxf(cnt[g], 1.0f);
    p[t] = sums[g * F + t] * inv;
    __syncthreads();
    float acc = bfc[t];
    for (int k = 0; k < F; ++k) acc = fmaf(p[k], Wfc[k * F + t], acc);
    z[g * F + t] = fmaxf(acc, 0.f);
}

// ---------------- out[t,g,c] = z[g,:] . Wh[t,:,c] + bh[t,c] ----------------
__global__ void k_head(const float* __restrict__ z, const float* __restrict__ Wh,
                       const float* __restrict__ bh, float* __restrict__ out) {
    int o = blockIdx.x * blockDim.x + threadIdx.x;
    if (o >= T * G * 2) return;
    int tt = o >> 9;        // / (G*2)
    int rem = o & 511;
    int g = rem >> 1;
    int c = rem & 1;
    float acc = bh[tt * 2 + c];
    const float* zr = &z[g * F];
    const float* wr = &Wh[tt * F * 2 + c];
    for (int h = 0; h < F; ++h) acc = fmaf(zr[h], wr[h * 2], acc);
    out[o] = acc;
}

extern "C" void kernel_launch(void* const* d_in, const int* in_sizes, int n_in,
                              void* d_out, int out_size, void* d_ws, size_t ws_size,
                              hipStream_t stream) {
    const float* x    = (const float*)d_in[0];
    const int*   ei   = (const int*)d_in[1];      // [2,E]: row0=src, row1=dst
    const int*   batch= (const int*)d_in[2];
    const float* W1   = (const float*)d_in[3];
    const float* b1   = (const float*)d_in[4];
    const float* W2   = (const float*)d_in[5];
    const float* b2   = (const float*)d_in[6];
    const float* Wfc  = (const float*)d_in[7];
    const float* bfc  = (const float*)d_in[8];
    const float* Wh   = (const float*)d_in[9];
    const float* bh   = (const float*)d_in[10];
    float* out = (float*)d_out;

    const int* srcp = ei;
    const int* dstp = ei + E;

    char* w = (char*)d_ws;
    auto alloc = [&](size_t bytes) {
        char* p = w;
        w += (bytes + 255) & ~(size_t)255;
        return p;
    };
    unsigned short* tmp16 = (unsigned short*)alloc((size_t)N * F * 2);
    unsigned short* hbuf16= (unsigned short*)alloc((size_t)N * F * 2);
    int2*  csr      = (int2*) alloc((size_t)E * 8);
    int*   rowstart = (int*)  alloc((size_t)(N + 1) * 4);
    int*   fillpos  = (int*)  alloc((size_t)N * 4);
    int*   deg8     = (int*)  alloc((size_t)8 * N * 4);
    int*   deg      = (int*)  alloc((size_t)N * 4);
    float* dinv     = (float*)alloc((size_t)N * 4);
    int*   part     = (int*)  alloc((size_t)NBLK * 4);
    float* sums     = (float*)alloc((size_t)G * F * 4);
    float* cnt      = (float*)alloc((size_t)G * 4);
    float* z        = (float*)alloc((size_t)G * F * 4);
    unsigned short* w1h = (unsigned short*)alloc((size_t)F * F * 2);
    unsigned short* w1l = (unsigned short*)alloc((size_t)F * F * 2);
    unsigned short* w2h = (unsigned short*)alloc((size_t)F * F * 2);
    unsigned short* w2l = (unsigned short*)alloc((size_t)F * F * 2);

    hipMemsetAsync(deg8, 0, (size_t)8 * N * 4, stream);

    // fused preamble: wcast W1/W2, cntbs, 8-way deg histogram, zero sums
    k_pre<<<PRE_BLKS, 256, 0, stream>>>(W1, W2, w1h, w1l, w2h, w2l,
                                        dstp, deg8, batch, cnt, sums);

    // CSR build (two-level parallel scan)
    k_part<<<NBLK, SCAN_B, 0, stream>>>(deg8, deg, part, dinv);
    k_scanpart<<<1, SCAN_B, 0, stream>>>(part);
    k_rowfill<<<NBLK, SCAN_B, 0, stream>>>(deg, part, rowstart, fillpos);

    // fused: layer-1 GEMM + XCD-partitioned CSR fill
    k_fillgemm<<<GB1 + FILL_BLKS, 256, 0, stream>>>(x, w1h, w1l, tmp16,
                                                    srcp, dstp, fillpos, dinv, csr);

    // layer 1 aggregation
    k_agg<<<(N * 16 + 255) / 256, 256, 0, stream>>>(tmp16, csr, rowstart, dinv, b1, hbuf16);
    // layer 2
    k_gemm<true><<<GB1, 256, 0, stream>>>(hbuf16, w2h, w2l, tmp16);
    k_agg<<<(N * 16 + 255) / 256, 256, 0, stream>>>(tmp16, csr, rowstart, dinv, b2, hbuf16);

    // pooling
    int ngrp = (N + 63) / 64;
    k_pool<<<(ngrp * 16 + 255) / 256, 256, 0, stream>>>(hbuf16, batch, sums);

    // fc + heads
    k_fc<<<G, 128, 0, stream>>>(sums, cnt, Wfc, bfc, z);
    k_head<<<(T * G * 2 + 255) / 256, 256, 0, stream>>>(z, Wh, bh, out);
}

// Round 9
// 302.811 us; speedup vs baseline: 2.0482x; 1.0248x over previous
//
#include <hip/hip_runtime.h>
#include <math.h>

constexpr int N = 50000;   // nodes
constexpr int E = 800000;  // edges (without self-loops)
constexpr int F = 128;     // features / hidden
constexpr int G = 256;     // graphs
constexpr int T = 4;       // tasks

constexpr int SCAN_B = 256;
constexpr int NBLK = (N + SCAN_B - 1) / SCAN_B;  // 196

// k_pre block-range layout
constexpr int WC_BLKS  = (F * F + 255) / 256;    // 64
constexpr int DEG_BLKS = (E + 255) / 256;        // 3125
constexpr int SUM_BLKS = (G * F + 255) / 256;    // 128
constexpr int PRE_DEG0 = 2 * WC_BLKS + 1;        // 129
constexpr int PRE_SUM0 = PRE_DEG0 + DEG_BLKS;    // 3254
constexpr int PRE_BLKS = PRE_SUM0 + SUM_BLKS;    // 3382

// fused fill+gemm1 layout (fill is full-lane now: one block per 256-edge chunk)
constexpr int GB1 = (N + 63) / 64;               // 782 gemm blocks

typedef __attribute__((ext_vector_type(8))) short short8;
typedef __attribute__((ext_vector_type(4))) float floatx4;

// bf16 <-> fp32 helpers (RNE on pack; values are finite)
__device__ inline float bf2f(unsigned short u) {
    union { unsigned int i; float f; } v;
    v.i = ((unsigned int)u) << 16;
    return v.f;
}
__device__ inline unsigned short f2bf(float f) {
    union { float f; unsigned int i; } v;
    v.f = f;
    unsigned int r = v.i + 0x7FFF + ((v.i >> 16) & 1);
    return (unsigned short)(r >> 16);
}
__device__ inline unsigned int pack2bf(float a, float b) {
    return (unsigned int)f2bf(a) | ((unsigned int)f2bf(b) << 16);
}

// pack W (fp32) -> MFMA-B-fragment order, hi/lo bf16 split
__device__ inline void wcast_one(const float* __restrict__ W,
                                 unsigned short* __restrict__ Whi,
                                 unsigned short* __restrict__ Wlo, int i) {
    if (i >= F * F) return;
    int k = i >> 7, n = i & 127;
    float w = W[i];
    unsigned short hi = f2bf(w);
    unsigned short lo = f2bf(w - bf2f(hi));
    int s = k >> 5, q = (k >> 3) & 3, j = k & 7;
    int idx = (((s * 128 + n) * 4 + q) * 8) + j;
    Whi[idx] = hi;
    Wlo[idx] = lo;
}

// ---------------- fused preamble: wcast(W1), wcast(W2), cntbs, deg8 hist, zero(sums) ----------------
// deg8[c][i], c = edge-chunk class (e>>8)&7: privatized histogram AND the
// basis for class-split fillpos sub-ranges used by the fill kernel.
__global__ __launch_bounds__(256) void k_pre(const float* __restrict__ W1, const float* __restrict__ W2,
                                             unsigned short* __restrict__ w1h, unsigned short* __restrict__ w1l,
                                             unsigned short* __restrict__ w2h, unsigned short* __restrict__ w2l,
                                             const int* __restrict__ dst, int* __restrict__ deg8,
                                             const int* __restrict__ batch, float* __restrict__ cnt,
                                             float* __restrict__ sums) {
    int b = blockIdx.x, t = threadIdx.x;
    if (b < WC_BLKS) {
        wcast_one(W1, w1h, w1l, b * 256 + t);
    } else if (b < 2 * WC_BLKS) {
        wcast_one(W2, w2h, w2l, (b - WC_BLKS) * 256 + t);
    } else if (b == 2 * WC_BLKS) {
        int g = t;
        int lo0 = 0, hi0 = N;
        while (lo0 < hi0) { int m = (lo0 + hi0) >> 1; if (batch[m] < g) lo0 = m + 1; else hi0 = m; }
        int lo1 = lo0, hi1 = N;
        while (lo1 < hi1) { int m = (lo1 + hi1) >> 1; if (batch[m] < g + 1) lo1 = m + 1; else hi1 = m; }
        cnt[g] = (float)(lo1 - lo0);
    } else if (b < PRE_SUM0) {
        int chunk = b - PRE_DEG0;
        int e = chunk * 256 + t;
        if (e < E) atomicAdd(&deg8[(chunk & 7) * N + dst[e]], 1);
    } else {
        int i = (b - PRE_SUM0) * 256 + t;
        if (i < G * F) sums[i] = 0.f;
    }
}

// ---------------- two-level scan: sum deg8 copies, block partials + dinv ----------------
__global__ __launch_bounds__(SCAN_B) void k_part(const int* __restrict__ deg8,
                                                 int* __restrict__ deg,
                                                 int* __restrict__ part,
                                                 float* __restrict__ dinv) {
    __shared__ int s[SCAN_B];
    int t = threadIdx.x;
    int i = blockIdx.x * SCAN_B + t;
    int v = 0;
    if (i < N) {
#pragma unroll
        for (int c = 0; c < 8; ++c) v += deg8[c * N + i];
        deg[i] = v;
        dinv[i] = rsqrtf((float)(v + 1));  // +1 self-loop
    }
    s[t] = v;
    __syncthreads();
#pragma unroll
    for (int off = SCAN_B / 2; off > 0; off >>= 1) {
        if (t < off) s[t] += s[t + off];
        __syncthreads();
    }
    if (t == 0) part[blockIdx.x] = s[0];
}

// ---------------- scan the 196 partials (exclusive) ----------------
__global__ __launch_bounds__(SCAN_B) void k_scanpart(int* __restrict__ part) {
    __shared__ int s[SCAN_B];
    int t = threadIdx.x;
    int v = (t < NBLK) ? part[t] : 0;
    s[t] = v;
    __syncthreads();
    for (int off = 1; off < SCAN_B; off <<= 1) {
        int u = (t >= off) ? s[t - off] : 0;
        __syncthreads();
        s[t] += u;
        __syncthreads();
    }
    if (t < NBLK) part[t] = s[t] - v;  // exclusive prefix of block sums
}

// ---------------- per-block scan + offset -> rowstart + class-split fillpos8 ----------------
__global__ __launch_bounds__(SCAN_B) void k_rowfill(const int* __restrict__ deg,
                                                    const int* __restrict__ deg8,
                                                    const int* __restrict__ part,
                                                    int* __restrict__ rowstart,
                                                    int* __restrict__ fillpos8) {
    __shared__ int s[SCAN_B];
    int t = threadIdx.x;
    int i = blockIdx.x * SCAN_B + t;
    int v = (i < N) ? deg[i] : 0;
    s[t] = v;
    __syncthreads();
    for (int off = 1; off < SCAN_B; off <<= 1) {
        int u = (t >= off) ? s[t - off] : 0;
        __syncthreads();
        s[t] += u;
        __syncthreads();
    }
    int excl = s[t] - v + part[blockIdx.x];
    if (i < N) {
        rowstart[i] = excl;
        int run = excl;
#pragma unroll
        for (int c = 0; c < 8; ++c) {        // disjoint per-class sub-ranges
            fillpos8[c * N + i] = run;
            run += deg8[c * N + i];
        }
    }
    if (blockIdx.x == 0 && t == 0) rowstart[N] = E;  // total degree == E
}

// ---------------- MFMA GEMM body: C16[64,128](bf16) = A-tile @ W ----------------
template <bool ABF16>
__device__ __forceinline__ void gemm_body(const void* __restrict__ Ain,
                                          const unsigned short* __restrict__ Wph,
                                          const unsigned short* __restrict__ Wpl,
                                          unsigned short* __restrict__ C16,
                                          int row0, int tid) {
    __shared__ __align__(16) unsigned short Albs[64 * 136];  // row-major, pad 136

    if (ABF16) {
        const uint4* A8 = (const uint4*)Ain;              // 16 uint4 per row
        for (int f = tid; f < 64 * 16; f += 256) {
            int r = f >> 4, kq = f & 15;
            int row = row0 + r;
            uint4 v = make_uint4(0u, 0u, 0u, 0u);
            if (row < N) v = A8[row * 16 + kq];
            *(uint4*)&Albs[r * 136 + kq * 8] = v;
        }
    } else {
        const float4* A4 = (const float4*)Ain;
        for (int f = tid; f < 64 * 32; f += 256) {
            int r = f >> 5, kq = f & 31;
            int row = row0 + r;
            float4 v = make_float4(0.f, 0.f, 0.f, 0.f);
            if (row < N) v = A4[row * 32 + kq];
            ushort4 o;
            o.x = f2bf(v.x); o.y = f2bf(v.y); o.z = f2bf(v.z); o.w = f2bf(v.w);
            *(ushort4*)&Albs[r * 136 + kq * 4] = o;
        }
    }
    __syncthreads();

    int wv = tid >> 6;        // wave 0..3 -> rows wv*16..wv*16+15
    int lane = tid & 63;
    int c16 = lane & 15;
    int q = lane >> 4;        // 0..3
    int m = wv * 16 + c16;

    floatx4 acc[8];
#pragma unroll
    for (int nt = 0; nt < 8; ++nt) acc[nt] = (floatx4){0.f, 0.f, 0.f, 0.f};

    const short8* WH = (const short8*)Wph;
    const short8* WL = (const short8*)Wpl;
#pragma unroll
    for (int s = 0; s < 4; ++s) {
        short8 a = *(const short8*)&Albs[m * 136 + s * 32 + q * 8];
        int wb = s * 512 + c16 * 4 + q;  // short8 units
#pragma unroll
        for (int nt = 0; nt < 8; ++nt) {
            acc[nt] = __builtin_amdgcn_mfma_f32_16x16x32_bf16(a, WH[wb + nt * 64], acc[nt], 0, 0, 0);
            acc[nt] = __builtin_amdgcn_mfma_f32_16x16x32_bf16(a, WL[wb + nt * 64], acc[nt], 0, 0, 0);
        }
    }

    // C/D layout: col = lane&15, row = (lane>>4)*4 + reg
    int rbase = row0 + wv * 16 + q * 4;
#pragma unroll
    for (int r = 0; r < 4; ++r) {
        int row = rbase + r;
        if (row < N) {
#pragma unroll
            for (int nt = 0; nt < 8; ++nt)
                C16[row * 128 + nt * 16 + c16] = f2bf(acc[nt][r]);
        }
    }
}

template <bool ABF16>
__global__ __launch_bounds__(256) void k_gemm(const void* __restrict__ Ain,
                                              const unsigned short* __restrict__ Wph,
                                              const unsigned short* __restrict__ Wpl,
                                              unsigned short* __restrict__ C16) {
    gemm_body<ABF16>(Ain, Wph, Wpl, C16, blockIdx.x * 64, threadIdx.x);
}

// ---------------- fused: gemm1 (blocks 0..GB1) + full-lane class-split CSR fill ----------------
__global__ __launch_bounds__(256) void k_fillgemm(const float* __restrict__ x,
                                                  const unsigned short* __restrict__ w1h,
                                                  const unsigned short* __restrict__ w1l,
                                                  unsigned short* __restrict__ tmp16,
                                                  const int* __restrict__ src,
                                                  const int* __restrict__ dst,
                                                  int* __restrict__ fillpos8,
                                                  const float* __restrict__ dinv,
                                                  int2* __restrict__ csr) {
    int b = blockIdx.x;
    if (b < GB1) {
        gemm_body<false>(x, w1h, w1l, tmp16, b * 64, threadIdx.x);
        return;
    }
    int chunk = b - GB1;                    // 0..DEG_BLKS-1
    int e = chunk * 256 + threadIdx.x;
    if (e >= E) return;
    int d = dst[e];
    int s = src[e];
    int pos = atomicAdd(&fillpos8[(chunk & 7) * N + d], 1);
    csr[pos] = make_int2(s, __float_as_int(dinv[s] * dinv[d]));
}

// 8 bf16 (uint4) fma into 8 fp32 accumulators
__device__ inline void fma8(const uint4& u, float c, float* acc) {
    union { unsigned int i; float f; } a;
    a.i = u.x << 16;          acc[0] = fmaf(a.f, c, acc[0]);
    a.i = u.x & 0xFFFF0000u;  acc[1] = fmaf(a.f, c, acc[1]);
    a.i = u.y << 16;          acc[2] = fmaf(a.f, c, acc[2]);
    a.i = u.y & 0xFFFF0000u;  acc[3] = fmaf(a.f, c, acc[3]);
    a.i = u.z << 16;          acc[4] = fmaf(a.f, c, acc[4]);
    a.i = u.z & 0xFFFF0000u;  acc[5] = fmaf(a.f, c, acc[5]);
    a.i = u.w << 16;          acc[6] = fmaf(a.f, c, acc[6]);
    a.i = u.w & 0xFFFF0000u;  acc[7] = fmaf(a.f, c, acc[7]);
}

// ---------------- gather aggregation (bf16 msgs, 16 lanes/row, 8x in flight) ----------------
__global__ __launch_bounds__(256) void k_agg(const unsigned short* __restrict__ tmp16,
                                             const int2* __restrict__ csr,
                                             const int* __restrict__ rowstart,
                                             const float* __restrict__ dinv,
                                             const float* __restrict__ bias,
                                             unsigned short* __restrict__ out16) {
    int node = (blockIdx.x * blockDim.x + threadIdx.x) >> 4;
    int lane = threadIdx.x & 15;           // 16 B per lane -> 256 B row
    if (node >= N) return;
    const uint4* t8 = (const uint4*)tmp16; // 16 uint4 per row
    float di = dinv[node];
    float c0 = di * di;                    // self-loop coefficient
    float acc[8] = {0.f, 0.f, 0.f, 0.f, 0.f, 0.f, 0.f, 0.f};
    fma8(t8[node * 16 + lane], c0, acc);

    int jb = rowstart[node], je = rowstart[node + 1];
    for (int j = jb; j < je; j += 8) {
        int2 e[8];
#pragma unroll
        for (int k = 0; k < 8; ++k) {
            int idx = j + k;
            int2 t = csr[idx < je ? idx : je - 1];
            if (idx >= je) t.y = 0;        // zero coef; duplicate src hits cache
            e[k] = t;
        }
        uint4 u[8];
#pragma unroll
        for (int k = 0; k < 8; ++k) u[k] = t8[e[k].x * 16 + lane];
#pragma unroll
        for (int k = 0; k < 8; ++k) fma8(u[k], __int_as_float(e[k].y), acc);
    }

    const float4* b4 = (const float4*)bias;
    float4 ba = b4[lane * 2], bb = b4[lane * 2 + 1];
    uint4 o;
    o.x = pack2bf(fmaxf(acc[0] + ba.x, 0.f), fmaxf(acc[1] + ba.y, 0.f));
    o.y = pack2bf(fmaxf(acc[2] + ba.z, 0.f), fmaxf(acc[3] + ba.w, 0.f));
    o.z = pack2bf(fmaxf(acc[4] + bb.x, 0.f), fmaxf(acc[5] + bb.y, 0.f));
    o.w = pack2bf(fmaxf(acc[6] + bb.z, 0.f), fmaxf(acc[7] + bb.w, 0.f));
    ((uint4*)out16)[node * 16 + lane] = o;
}

// ---------------- mean-pool accumulate over bf16 h (batch is sorted) ----------------
__global__ void k_pool(const unsigned short* __restrict__ h16, const int* __restrict__ batch,
                       float* __restrict__ sums) {
    int grp = (blockIdx.x * blockDim.x + threadIdx.x) >> 4;
    int lane = threadIdx.x & 15;
    int base = grp * 64;
    if (base >= N) return;
    int end = (base + 64 < N) ? base + 64 : N;
    float acc[8] = {0.f, 0.f, 0.f, 0.f, 0.f, 0.f, 0.f, 0.f};
    const uint4* h4 = (const uint4*)h16;
    int curb = batch[base];
    for (int i = base; i < end; ++i) {
        int b = batch[i];
        if (b != curb) {
            float* sp = &sums[curb * F + lane * 8];
#pragma unroll
            for (int k = 0; k < 8; ++k) { atomicAdd(sp + k, acc[k]); acc[k] = 0.f; }
            curb = b;
        }
        fma8(h4[i * 16 + lane], 1.0f, acc);
    }
    float* sp = &sums[curb * F + lane * 8];
#pragma unroll
    for (int k = 0; k < 8; ++k) atomicAdd(sp + k, acc[k]);
}

// ---------------- z = relu(pooled @ Wfc + bfc) ----------------
__global__ __launch_bounds__(128) void k_fc(const float* __restrict__ sums,
                                            const float* __restrict__ cnt,
                                            const float* __restrict__ Wfc,
                                            const float* __restrict__ bfc,
                                            float* __restrict__ z) {
    __shared__ float p[128];
    int g = blockIdx.x, t = threadIdx.x;
    float inv = 1.0f / fmaxf(cnt[g], 1.0f);
    p[t] = sums[g * F + t] * inv;
    __syncthreads();
    float acc = bfc[t];
    for (int k = 0; k < F; ++k) acc = fmaf(p[k], Wfc[k * F + t], acc);
    z[g * F + t] = fmaxf(acc, 0.f);
}

// ---------------- out[t,g,c] = z[g,:] . Wh[t,:,c] + bh[t,c] ----------------
__global__ void k_head(const float* __restrict__ z, const float* __restrict__ Wh,
                       const float* __restrict__ bh, float* __restrict__ out) {
    int o = blockIdx.x * blockDim.x + threadIdx.x;
    if (o >= T * G * 2) return;
    int tt = o >> 9;        // / (G*2)
    int rem = o & 511;
    int g = rem >> 1;
    int c = rem & 1;
    float acc = bh[tt * 2 + c];
    const float* zr = &z[g * F];
    const float* wr = &Wh[tt * F * 2 + c];
    for (int h = 0; h < F; ++h) acc = fmaf(zr[h], wr[h * 2], acc);
    out[o] = acc;
}

extern "C" void kernel_launch(void* const* d_in, const int* in_sizes, int n_in,
                              void* d_out, int out_size, void* d_ws, size_t ws_size,
                              hipStream_t stream) {
    const float* x    = (const float*)d_in[0];
    const int*   ei   = (const int*)d_in[1];      // [2,E]: row0=src, row1=dst
    const int*   batch= (const int*)d_in[2];
    const float* W1   = (const float*)d_in[3];
    const float* b1   = (const float*)d_in[4];
    const float* W2   = (const float*)d_in[5];
    const float* b2   = (const float*)d_in[6];
    const float* Wfc  = (const float*)d_in[7];
    const float* bfc  = (const float*)d_in[8];
    const float* Wh   = (const float*)d_in[9];
    const float* bh   = (const float*)d_in[10];
    float* out = (float*)d_out;

    const int* srcp = ei;
    const int* dstp = ei + E;

    char* w = (char*)d_ws;
    auto alloc = [&](size_t bytes) {
        char* p = w;
        w += (bytes + 255) & ~(size_t)255;
        return p;
    };
    unsigned short* tmp16 = (unsigned short*)alloc((size_t)N * F * 2);
    unsigned short* hbuf16= (unsigned short*)alloc((size_t)N * F * 2);
    int2*  csr      = (int2*) alloc((size_t)E * 8);
    int*   rowstart = (int*)  alloc((size_t)(N + 1) * 4);
    int*   fillpos8 = (int*)  alloc((size_t)8 * N * 4);
    int*   deg8     = (int*)  alloc((size_t)8 * N * 4);
    int*   deg      = (int*)  alloc((size_t)N * 4);
    float* dinv     = (float*)alloc((size_t)N * 4);
    int*   part     = (int*)  alloc((size_t)NBLK * 4);
    float* sums     = (float*)alloc((size_t)G * F * 4);
    float* cnt      = (float*)alloc((size_t)G * 4);
    float* z        = (float*)alloc((size_t)G * F * 4);
    unsigned short* w1h = (unsigned short*)alloc((size_t)F * F * 2);
    unsigned short* w1l = (unsigned short*)alloc((size_t)F * F * 2);
    unsigned short* w2h = (unsigned short*)alloc((size_t)F * F * 2);
    unsigned short* w2l = (unsigned short*)alloc((size_t)F * F * 2);

    hipMemsetAsync(deg8, 0, (size_t)8 * N * 4, stream);

    // fused preamble: wcast W1/W2, cntbs, 8-way deg histogram, zero sums
    k_pre<<<PRE_BLKS, 256, 0, stream>>>(W1, W2, w1h, w1l, w2h, w2l,
                                        dstp, deg8, batch, cnt, sums);

    // CSR build (two-level parallel scan; class-split fillpos8)
    k_part<<<NBLK, SCAN_B, 0, stream>>>(deg8, deg, part, dinv);
    k_scanpart<<<1, SCAN_B, 0, stream>>>(part);
    k_rowfill<<<NBLK, SCAN_B, 0, stream>>>(deg, deg8, part, rowstart, fillpos8);

    // fused: layer-1 GEMM + full-lane class-split CSR fill
    k_fillgemm<<<GB1 + DEG_BLKS, 256, 0, stream>>>(x, w1h, w1l, tmp16,
                                                   srcp, dstp, fillpos8, dinv, csr);

    // layer 1 aggregation
    k_agg<<<(N * 16 + 255) / 256, 256, 0, stream>>>(tmp16, csr, rowstart, dinv, b1, hbuf16);
    // layer 2
    k_gemm<true><<<GB1, 256, 0, stream>>>(hbuf16, w2h, w2l, tmp16);
    k_agg<<<(N * 16 + 255) / 256, 256, 0, stream>>>(tmp16, csr, rowstart, dinv, b2, hbuf16);

    // pooling
    int ngrp = (N + 63) / 64;
    k_pool<<<(ngrp * 16 + 255) / 256, 256, 0, stream>>>(hbuf16, batch, sums);

    // fc + heads
    k_fc<<<G, 128, 0, stream>>>(sums, cnt, Wfc, bfc, z);
    k_head<<<(T * G * 2 + 255) / 256, 256, 0, stream>>>(z, Wh, bh, out);
}